// Round 1
// baseline (988.672 us; speedup 1.0000x reference)
//
#include <hip/hip_runtime.h>
#include <math.h>

// ---------------- workspace layout (float offsets) ----------------
// pool1 region (94.4MB) is reused after conv2 for pool2/h_raw/mu.
static const size_t F_POOL1 = 0;                  // 8192*20*144   = 23,592,960
static const size_t F_C2    = 23592960;           // 8192*50*64    = 26,214,400
static const size_t F_PART1 = 49807360;           // 8192*40       = 327,680
static const size_t F_PART2 = 50135040;           // 2048*100      = 204,800
static const size_t F_PART3 = 50339840;           // 32*20         = 640
static const size_t F_BN1   = 50340480;           // 40
static const size_t F_BN2   = 50340520;           // 100
static const size_t F_BN3   = 50340620;           // 20
static const size_t F_SRAW  = 50340640;           // 2560
static const size_t F_PINEW = 50343200;           // 2560
// overlays inside pool1 region (pool1 dead after k_conv2):
static const size_t F_POOL2 = 0;                  // 8192*800 = 6,553,600
static const size_t F_HRAW  = 6553600;            // 8192*10  = 81,920
static const size_t F_MU    = 6635520;            // 8192*256 = 2,097,152

__device__ __forceinline__ float relu_(float v) { return v > 0.f ? v : 0.f; }

// ---- conv1 (28x28 -> 20x24x24) + per-channel partial sums, no store ----
__global__ __launch_bounds__(256) void k_conv1_stats(
    const float* __restrict__ x, const float* __restrict__ w,
    const float* __restrict__ bias, float* __restrict__ part)
{
  __shared__ alignas(16) float xs[784];
  __shared__ float wsh[500];
  __shared__ float bsh[20];
  __shared__ float ssum[20], ssq[20];
  const int tid = threadIdx.x;
  const int img = blockIdx.x;
  const float* xp = x + (size_t)img * 784;
  for (int i = tid; i < 784; i += 256) xs[i] = xp[i];
  for (int i = tid; i < 500; i += 256) wsh[i] = w[i];
  if (tid < 20) { bsh[tid] = bias[tid]; ssum[tid] = 0.f; ssq[tid] = 0.f; }
  __syncthreads();
  // 480 tasks = 24 rows x 20 oc ; oy-major so LDS-atomic targets spread in-wave
  for (int t = tid; t < 480; t += 256) {
    const int oy = t / 20, oc = t % 20;
    float acc[24];
    const float bv = bsh[oc];
    #pragma unroll
    for (int j = 0; j < 24; ++j) acc[j] = bv;
    #pragma unroll
    for (int kh = 0; kh < 5; ++kh) {
      const float* row = &xs[(oy + kh) * 28];
      float r[28];
      #pragma unroll
      for (int j = 0; j < 7; ++j) {
        const float4 v = *(const float4*)(row + 4 * j);
        r[4*j] = v.x; r[4*j+1] = v.y; r[4*j+2] = v.z; r[4*j+3] = v.w;
      }
      #pragma unroll
      for (int kw = 0; kw < 5; ++kw) {
        const float wv = wsh[oc*25 + kh*5 + kw];
        #pragma unroll
        for (int j = 0; j < 24; ++j) acc[j] += r[j + kw] * wv;
      }
    }
    float s = 0.f, q = 0.f;
    #pragma unroll
    for (int j = 0; j < 24; ++j) { s += acc[j]; q += acc[j] * acc[j]; }
    atomicAdd(&ssum[oc], s);
    atomicAdd(&ssq[oc], q);
  }
  __syncthreads();
  if (tid < 20) {
    part[(size_t)img*40 + tid]      = ssum[tid];
    part[(size_t)img*40 + 20 + tid] = ssq[tid];
  }
}

// ---- conv1 again + BN + ReLU + 2x2 maxpool -> pool1 (B,20,12,12) ----
__global__ __launch_bounds__(256) void k_conv1_pool(
    const float* __restrict__ x, const float* __restrict__ w,
    const float* __restrict__ bias, const float* __restrict__ bn,
    float* __restrict__ pool1)
{
  __shared__ alignas(16) float xs[784];
  __shared__ float wsh[500];
  __shared__ float bsh[20], scs[20], shs[20];
  const int tid = threadIdx.x;
  const int img = blockIdx.x;
  const float* xp = x + (size_t)img * 784;
  for (int i = tid; i < 784; i += 256) xs[i] = xp[i];
  for (int i = tid; i < 500; i += 256) wsh[i] = w[i];
  if (tid < 20) { bsh[tid] = bias[tid]; scs[tid] = bn[tid]; shs[tid] = bn[20 + tid]; }
  __syncthreads();
  // 240 tasks = 20 oc x 12 pooled-rows ; oc-major so writes coalesce
  if (tid < 240) {
    const int oc = tid / 12, py = tid % 12;
    float acc[2][24];
    const float bv = bsh[oc];
    #pragma unroll
    for (int r = 0; r < 2; ++r)
      #pragma unroll
      for (int j = 0; j < 24; ++j) acc[r][j] = bv;
    #pragma unroll
    for (int r = 0; r < 2; ++r) {
      const int oy = 2 * py + r;
      #pragma unroll
      for (int kh = 0; kh < 5; ++kh) {
        const float* row = &xs[(oy + kh) * 28];
        float rr[28];
        #pragma unroll
        for (int j = 0; j < 7; ++j) {
          const float4 v = *(const float4*)(row + 4 * j);
          rr[4*j] = v.x; rr[4*j+1] = v.y; rr[4*j+2] = v.z; rr[4*j+3] = v.w;
        }
        #pragma unroll
        for (int kw = 0; kw < 5; ++kw) {
          const float wv = wsh[oc*25 + kh*5 + kw];
          #pragma unroll
          for (int j = 0; j < 24; ++j) acc[r][j] += rr[j + kw] * wv;
        }
      }
    }
    const float scv = scs[oc], shv = shs[oc];
    float o[12];
    #pragma unroll
    for (int j = 0; j < 12; ++j) {
      float a = relu_(acc[0][2*j]   * scv + shv);
      float b = relu_(acc[0][2*j+1] * scv + shv);
      float c = relu_(acc[1][2*j]   * scv + shv);
      float d = relu_(acc[1][2*j+1] * scv + shv);
      o[j] = fmaxf(fmaxf(a, b), fmaxf(c, d));
    }
    float* dst = pool1 + (size_t)img*2880 + oc*144 + py*12;
    #pragma unroll
    for (int j = 0; j < 3; ++j) {
      float4 v; v.x = o[4*j]; v.y = o[4*j+1]; v.z = o[4*j+2]; v.w = o[4*j+3];
      *(float4*)(dst + 4*j) = v;
    }
  }
}

// ---- conv2 (20x12x12 -> 50x8x8) + per-channel partial sums ----
// block = 4 waves, 4 images staged in LDS; wave owns one oc (wave-uniform
// weights -> scalar loads); lane = (img, oy, ox4) computes 4 pixels by
// sliding-window from two ds_read_b128.
__global__ __launch_bounds__(256) void k_conv2(
    const float* __restrict__ pool1, const float* __restrict__ w,
    const float* __restrict__ bias, float* __restrict__ outraw,
    float* __restrict__ part)
{
  __shared__ alignas(16) float in4[11520];
  const int tid = threadIdx.x;
  const int blk = blockIdx.x;
  const float* src = pool1 + (size_t)blk * 11520;
  for (int i = tid; i < 2880; i += 256)
    ((float4*)in4)[i] = ((const float4*)src)[i];
  __syncthreads();
  const int wave = tid >> 6, lane = tid & 63;
  const int img = lane >> 4;
  const int pos = lane & 15;
  const int oy = pos >> 1, ox4 = (pos & 1) * 4;
  const float* bin = &in4[img*2880 + oy*12 + ox4];
  for (int k = 0; k < 13; ++k) {
    int oc = wave + 4*k;
    if (oc >= 50) break;                       // wave-uniform branch
    oc = __builtin_amdgcn_readfirstlane(oc);
    const float* wp = w + oc*500;
    float a0, a1, a2, a3;
    a0 = a1 = a2 = a3 = bias[oc];
    #pragma unroll 2
    for (int ic = 0; ic < 20; ++ic) {
      const float* ip = bin + ic*144;
      const float* wr = wp + ic*25;
      #pragma unroll
      for (int kh = 0; kh < 5; ++kh) {
        const float4 v0 = *(const float4*)(ip + kh*12);
        const float4 v1 = *(const float4*)(ip + kh*12 + 4);
        const float r0 = v0.x, r1 = v0.y, r2 = v0.z, r3 = v0.w;
        const float r4 = v1.x, r5 = v1.y, r6 = v1.z, r7 = v1.w;
        const float w0 = wr[kh*5+0], w1 = wr[kh*5+1], w2 = wr[kh*5+2];
        const float w3 = wr[kh*5+3], w4 = wr[kh*5+4];
        a0 += r0*w0 + r1*w1 + r2*w2 + r3*w3 + r4*w4;
        a1 += r1*w0 + r2*w1 + r3*w2 + r4*w3 + r5*w4;
        a2 += r2*w0 + r3*w1 + r4*w2 + r5*w3 + r6*w4;
        a3 += r3*w0 + r4*w1 + r5*w2 + r6*w3 + r7*w4;
      }
    }
    float4 o; o.x = a0; o.y = a1; o.z = a2; o.w = a3;
    *(float4*)(outraw + (size_t)(blk*4 + img)*3200 + oc*64 + oy*8 + ox4) = o;
    float s = a0 + a1 + a2 + a3;
    float q = a0*a0 + a1*a1 + a2*a2 + a3*a3;
    #pragma unroll
    for (int off = 32; off > 0; off >>= 1) { s += __shfl_down(s, off); q += __shfl_down(q, off); }
    if (lane == 0) {
      part[(size_t)blk*100 + oc]      = s;
      part[(size_t)blk*100 + 50 + oc] = q;
    }
  }
}

// ---- BN finalize: reduce per-block partials (double), emit scale/shift ----
__global__ __launch_bounds__(256) void k_bn_fin(
    const float* __restrict__ part, int nblk, int nch, float N,
    const float* __restrict__ g, const float* __restrict__ b,
    float* __restrict__ out)
{
  __shared__ double rd[4][2];
  const int tid = threadIdx.x, ch = blockIdx.x;
  const int lane = tid & 63, wid = tid >> 6;
  double s = 0.0, q = 0.0;
  for (int i = tid; i < nblk; i += 256) {
    s += (double)part[(size_t)i*2*nch + ch];
    q += (double)part[(size_t)i*2*nch + nch + ch];
  }
  #pragma unroll
  for (int off = 32; off > 0; off >>= 1) { s += __shfl_down(s, off); q += __shfl_down(q, off); }
  if (lane == 0) { rd[wid][0] = s; rd[wid][1] = q; }
  __syncthreads();
  if (tid == 0) {
    double S = rd[0][0] + rd[1][0] + rd[2][0] + rd[3][0];
    double Q = rd[0][1] + rd[1][1] + rd[2][1] + rd[3][1];
    double mean = S / (double)N;
    double var  = Q / (double)N - mean * mean;
    if (var < 0.0) var = 0.0;
    float scv = (float)((double)g[ch] / sqrt(var + 1e-5));
    out[ch]       = scv;
    out[nch + ch] = b[ch] - (float)mean * scv;
  }
}

// ---- BN2 + ReLU + 2x2 maxpool: (B,50,8,8) -> pool2 (B,800) ----
__global__ __launch_bounds__(256) void k_bnpool2(
    const float* __restrict__ raw, const float* __restrict__ bn2,
    float* __restrict__ pool2)
{
  const int gid = blockIdx.x * 256 + threadIdx.x;   // 6,553,600 total
  const int b = gid / 800, r = gid % 800;
  const int oc = r >> 4, p = r & 15, py = p >> 2, px = p & 3;
  const float sc = bn2[oc], sh = bn2[50 + oc];
  const float* base = raw + (size_t)b*3200 + oc*64 + py*16 + px*2;
  float v0 = relu_(base[0]*sc + sh);
  float v1 = relu_(base[1]*sc + sh);
  float v2 = relu_(base[8]*sc + sh);
  float v3 = relu_(base[9]*sc + sh);
  pool2[gid] = fmaxf(fmaxf(v0, v1), fmaxf(v2, v3));
}

// ---- fc1: (B,800)x(10,800)^T + bias, + per-feature partial stats ----
__global__ __launch_bounds__(256) void k_fc1(
    const float* __restrict__ pool2, const float* __restrict__ w,
    const float* __restrict__ bias, float* __restrict__ h_raw,
    float* __restrict__ part)
{
  __shared__ alignas(16) float wl[8000];
  __shared__ float bsh[10];
  __shared__ float red[4][20];
  const int tid = threadIdx.x;
  for (int i = tid; i < 2000; i += 256)
    ((float4*)wl)[i] = ((const float4*)w)[i];
  if (tid < 10) bsh[tid] = bias[tid];
  __syncthreads();
  const int b = blockIdx.x * 256 + tid;
  const float* xr = pool2 + (size_t)b * 800;
  float acc[10];
  #pragma unroll
  for (int f = 0; f < 10; ++f) acc[f] = bsh[f];
  for (int k = 0; k < 800; k += 4) {
    const float4 v = *(const float4*)(xr + k);
    #pragma unroll
    for (int f = 0; f < 10; ++f) {
      const float4 wv = *(const float4*)(wl + f*800 + k);
      acc[f] += v.x*wv.x + v.y*wv.y + v.z*wv.z + v.w*wv.w;
    }
  }
  #pragma unroll
  for (int f = 0; f < 10; ++f) h_raw[(size_t)b*10 + f] = acc[f];
  const int lane = tid & 63, wid = tid >> 6;
  #pragma unroll
  for (int f = 0; f < 10; ++f) {
    float sv = acc[f], qv = acc[f]*acc[f];
    #pragma unroll
    for (int off = 32; off > 0; off >>= 1) { sv += __shfl_down(sv, off); qv += __shfl_down(qv, off); }
    if (lane == 0) { red[wid][f] = sv; red[wid][10+f] = qv; }
  }
  __syncthreads();
  if (tid < 20)
    part[(size_t)blockIdx.x*20 + tid] = red[0][tid] + red[1][tid] + red[2][tid] + red[3][tid];
}

// ---- BN3+ReLU on h, theta logits -> sigmoid p, tree walk -> mu ----
__global__ __launch_bounds__(256) void k_theta_mu(
    const float* __restrict__ h_raw, const float* __restrict__ bn3,
    const float* __restrict__ tw, const float* __restrict__ tb,
    float* __restrict__ mu)
{
  __shared__ float twl[2550];
  __shared__ float hl[10];
  __shared__ float pl[256];
  const int tid = threadIdx.x, b = blockIdx.x;
  for (int i = tid; i < 2550; i += 256) twl[i] = tw[i];
  if (tid < 10) {
    float v = h_raw[(size_t)b*10 + tid] * bn3[tid] + bn3[10 + tid];
    hl[tid] = relu_(v);
  }
  __syncthreads();
  if (tid < 255) {
    float d = tb[tid];
    #pragma unroll
    for (int f = 0; f < 10; ++f) d += hl[f] * twl[tid*10 + f];
    pl[tid] = 1.f / (1.f + expf(-d));
  }
  __syncthreads();
  // preorder walk: right child of node at depth d(=k+1) is idx + 2^(7-k)
  float m = 1.f; int idx = 0;
  #pragma unroll
  for (int k = 0; k < 8; ++k) {
    const int dir = (tid >> (7 - k)) & 1;
    const float pv = pl[idx];
    m *= dir ? pv : (1.f - pv);
    idx += dir ? (1 << (7 - k)) : 1;
  }
  mu[(size_t)b*256 + tid] = m;
}

// ---- S_raw[l,c] = sum over samples of class c of mu[b,l] ----
__global__ __launch_bounds__(256) void k_S(
    const float* __restrict__ mu, const int* __restrict__ y,
    float* __restrict__ S)
{
  const int tid = threadIdx.x;      // = leaf
  const int b0 = blockIdx.x * 64;
  float acc[10];
  #pragma unroll
  for (int c = 0; c < 10; ++c) acc[c] = 0.f;
  for (int s = 0; s < 64; ++s) {
    const int b = b0 + s;
    const float m = mu[(size_t)b*256 + tid];
    const int c = y[b];
    #pragma unroll
    for (int cc = 0; cc < 10; ++cc) acc[cc] += (c == cc) ? m : 0.f;
  }
  #pragma unroll
  for (int cc = 0; cc < 10; ++cc) atomicAdd(&S[tid*10 + cc], acc[cc]);
}

// ---- pi EM update (tiny, one block; thread = leaf) ----
__global__ __launch_bounds__(256) void k_pi(
    const float* __restrict__ pi, const float* __restrict__ S,
    float* __restrict__ pi_new)
{
  __shared__ float pin[2560];
  __shared__ float Pp[10];
  const int t = threadIdx.x;
  float row[10]; float rs = 0.f;
  #pragma unroll
  for (int c = 0; c < 10; ++c) { row[c] = pi[t*10 + c]; rs += row[c]; }
  #pragma unroll
  for (int c = 0; c < 10; ++c) { row[c] /= rs; pin[t*10 + c] = row[c]; }
  __syncthreads();
  if (t < 10) {
    float s = 0.f;
    for (int l = 0; l < 256; ++l) s += pin[l*10 + t];
    Pp[t] = s / 256.f;
  }
  __syncthreads();
  float hs = 0.f; float ph[10];
  #pragma unroll
  for (int c = 0; c < 10; ++c) {
    const float Sv = S[t*10 + c] / Pp[c];
    ph[c] = row[c] * Sv;
    hs += ph[c];
  }
  #pragma unroll
  for (int c = 0; c < 10; ++c) pi_new[t*10 + c] = ph[c] / hs;
}

// ---- out = log(mu @ pi_new) ----
__global__ __launch_bounds__(256) void k_out(
    const float* __restrict__ mu, const float* __restrict__ pn,
    float* __restrict__ out)
{
  __shared__ float pl[2560];
  const int tid = threadIdx.x;
  for (int i = tid; i < 2560; i += 256) pl[i] = pn[i];
  __syncthreads();
  const int gid = blockIdx.x * 256 + tid;   // 81920 total
  const int b = gid / 10, c = gid % 10;
  const float* mr = mu + (size_t)b * 256;
  float acc = 0.f;
  for (int l = 0; l < 256; ++l) acc += mr[l] * pl[l*10 + c];
  out[gid] = logf(acc);
}

extern "C" void kernel_launch(void* const* d_in, const int* in_sizes, int n_in,
                              void* d_out, int out_size, void* d_ws, size_t ws_size,
                              hipStream_t stream)
{
  const float* x   = (const float*)d_in[0];
  const int*   y   = (const int*)  d_in[1];
  const float* c1w = (const float*)d_in[2];
  const float* c1b = (const float*)d_in[3];
  const float* c2w = (const float*)d_in[4];
  const float* c2b = (const float*)d_in[5];
  const float* g1  = (const float*)d_in[6];
  const float* be1 = (const float*)d_in[7];
  const float* g2  = (const float*)d_in[8];
  const float* be2 = (const float*)d_in[9];
  const float* fw  = (const float*)d_in[10];
  const float* fb  = (const float*)d_in[11];
  const float* g3  = (const float*)d_in[12];
  const float* be3 = (const float*)d_in[13];
  const float* thw = (const float*)d_in[14];
  const float* thb = (const float*)d_in[15];
  const float* pi  = (const float*)d_in[16];
  float* ws  = (float*)d_ws;
  float* out = (float*)d_out;

  float* pool1 = ws + F_POOL1;
  float* c2raw = ws + F_C2;
  float* part1 = ws + F_PART1;
  float* part2 = ws + F_PART2;
  float* part3 = ws + F_PART3;
  float* bn1   = ws + F_BN1;
  float* bn2   = ws + F_BN2;
  float* bn3   = ws + F_BN3;
  float* sraw  = ws + F_SRAW;
  float* pinew = ws + F_PINEW;
  float* pool2 = ws + F_POOL2;   // overlays pool1 region (pool1 dead by then)
  float* hraw  = ws + F_HRAW;
  float* muB   = ws + F_MU;

  hipMemsetAsync(sraw, 0, 2560 * sizeof(float), stream);

  k_conv1_stats<<<8192, 256, 0, stream>>>(x, c1w, c1b, part1);
  k_bn_fin<<<20, 256, 0, stream>>>(part1, 8192, 20, 8192.f * 576.f, g1, be1, bn1);
  k_conv1_pool<<<8192, 256, 0, stream>>>(x, c1w, c1b, bn1, pool1);
  k_conv2<<<2048, 256, 0, stream>>>(pool1, c2w, c2b, c2raw, part2);
  k_bn_fin<<<50, 256, 0, stream>>>(part2, 2048, 50, 8192.f * 64.f, g2, be2, bn2);
  k_bnpool2<<<25600, 256, 0, stream>>>(c2raw, bn2, pool2);
  k_fc1<<<32, 256, 0, stream>>>(pool2, fw, fb, hraw, part3);
  k_bn_fin<<<10, 256, 0, stream>>>(part3, 32, 10, 8192.f, g3, be3, bn3);
  k_theta_mu<<<8192, 256, 0, stream>>>(hraw, bn3, thw, thb, muB);
  k_S<<<128, 256, 0, stream>>>(muB, y, sraw);
  k_pi<<<1, 256, 0, stream>>>(pi, sraw, pinew);
  k_out<<<320, 256, 0, stream>>>(muB, pinew, out);
}

// Round 2
// 442.133 us; speedup vs baseline: 2.2361x; 2.2361x over previous
//
#include <hip/hip_runtime.h>
#include <hip/hip_bf16.h>
#include <math.h>

typedef __attribute__((ext_vector_type(8))) short short8v;
typedef __attribute__((ext_vector_type(4))) float float4v;

// ---------------- workspace layout (float/dword offsets) ----------------
static const size_t F_POOL1T = 0;              // bf16 ch-last: 8192 imgs * 1728 dwords
static const size_t F_C2     = 14155776;       // fp32 NCHW [8192][50][64] = 26,214,400
static const size_t F_PART1  = 40370176;       // 8192*40
static const size_t F_PART2  = 40697856;       // 2048*100
static const size_t F_PART3  = 40902656;       // 32*20
static const size_t F_BN1    = 40903296;       // 40
static const size_t F_BN2    = 40903336;       // 100
static const size_t F_BN3    = 40903436;       // 20
static const size_t F_SRAW   = 40903456;       // 2560
static const size_t F_PINEW  = 40906016;       // 2560
static const size_t F_WB     = 40908576;       // 19456 dwords (76*64*8 bf16)
// overlays in pool1t region (dead after conv2):
static const size_t F_POOL2  = 0;              // 8192*800
static const size_t F_HRAW   = 6553600;        // 8192*10
static const size_t F_MU     = 6635520;        // 8192*256

__device__ __forceinline__ float relu_(float v) { return v > 0.f ? v : 0.f; }

__device__ __forceinline__ unsigned int pack_bf16x2(float a, float b) {
  __hip_bfloat16 ha = __float2bfloat16(a), hb = __float2bfloat16(b);
  unsigned short ua, ub;
  __builtin_memcpy(&ua, &ha, 2); __builtin_memcpy(&ub, &hb, 2);
  return ((unsigned int)ub << 16) | ua;
}

// ---- conv1 (28x28 -> 20x24x24) + per-channel partial sums, no store ----
__global__ __launch_bounds__(256) void k_conv1_stats(
    const float* __restrict__ x, const float* __restrict__ w,
    const float* __restrict__ bias, float* __restrict__ part)
{
  __shared__ alignas(16) float xs[784];
  __shared__ float wsh[500];
  __shared__ float bsh[20];
  __shared__ float ssum[20], ssq[20];
  const int tid = threadIdx.x;
  const int img = blockIdx.x;
  const float* xp = x + (size_t)img * 784;
  for (int i = tid; i < 784; i += 256) xs[i] = xp[i];
  for (int i = tid; i < 500; i += 256) wsh[i] = w[i];
  if (tid < 20) { bsh[tid] = bias[tid]; ssum[tid] = 0.f; ssq[tid] = 0.f; }
  __syncthreads();
  for (int t = tid; t < 480; t += 256) {
    const int oy = t / 20, oc = t % 20;
    float acc[24];
    const float bv = bsh[oc];
    #pragma unroll
    for (int j = 0; j < 24; ++j) acc[j] = bv;
    #pragma unroll
    for (int kh = 0; kh < 5; ++kh) {
      const float* row = &xs[(oy + kh) * 28];
      float r[28];
      #pragma unroll
      for (int j = 0; j < 7; ++j) {
        const float4 v = *(const float4*)(row + 4 * j);
        r[4*j] = v.x; r[4*j+1] = v.y; r[4*j+2] = v.z; r[4*j+3] = v.w;
      }
      #pragma unroll
      for (int kw = 0; kw < 5; ++kw) {
        const float wv = wsh[oc*25 + kh*5 + kw];
        #pragma unroll
        for (int j = 0; j < 24; ++j) acc[j] += r[j + kw] * wv;
      }
    }
    float s = 0.f, q = 0.f;
    #pragma unroll
    for (int j = 0; j < 24; ++j) { s += acc[j]; q += acc[j] * acc[j]; }
    atomicAdd(&ssum[oc], s);
    atomicAdd(&ssq[oc], q);
  }
  __syncthreads();
  if (tid < 20) {
    part[(size_t)img*40 + tid]      = ssum[tid];
    part[(size_t)img*40 + 20 + tid] = ssq[tid];
  }
}

// ---- conv1 + BN + ReLU + pool -> pool1t bf16 channel-last [img][144][24] ----
__global__ __launch_bounds__(256) void k_conv1_pool(
    const float* __restrict__ x, const float* __restrict__ w,
    const float* __restrict__ bias, const float* __restrict__ bn,
    unsigned int* __restrict__ pool1t)
{
  __shared__ alignas(16) float xs[784];
  __shared__ float wsh[500];
  __shared__ float bsh[20], scs[20], shs[20];
  __shared__ float tt[20][144];
  const int tid = threadIdx.x;
  const int img = blockIdx.x;
  const float* xp = x + (size_t)img * 784;
  for (int i = tid; i < 784; i += 256) xs[i] = xp[i];
  for (int i = tid; i < 500; i += 256) wsh[i] = w[i];
  if (tid < 20) { bsh[tid] = bias[tid]; scs[tid] = bn[tid]; shs[tid] = bn[20 + tid]; }
  __syncthreads();
  if (tid < 240) {
    const int oc = tid / 12, py = tid % 12;
    float acc[2][24];
    const float bv = bsh[oc];
    #pragma unroll
    for (int r = 0; r < 2; ++r)
      #pragma unroll
      for (int j = 0; j < 24; ++j) acc[r][j] = bv;
    #pragma unroll
    for (int r = 0; r < 2; ++r) {
      const int oy = 2 * py + r;
      #pragma unroll
      for (int kh = 0; kh < 5; ++kh) {
        const float* row = &xs[(oy + kh) * 28];
        float rr[28];
        #pragma unroll
        for (int j = 0; j < 7; ++j) {
          const float4 v = *(const float4*)(row + 4 * j);
          rr[4*j] = v.x; rr[4*j+1] = v.y; rr[4*j+2] = v.z; rr[4*j+3] = v.w;
        }
        #pragma unroll
        for (int kw = 0; kw < 5; ++kw) {
          const float wv = wsh[oc*25 + kh*5 + kw];
          #pragma unroll
          for (int j = 0; j < 24; ++j) acc[r][j] += rr[j + kw] * wv;
        }
      }
    }
    const float scv = scs[oc], shv = shs[oc];
    #pragma unroll
    for (int j = 0; j < 12; ++j) {
      float a = relu_(acc[0][2*j]   * scv + shv);
      float b = relu_(acc[0][2*j+1] * scv + shv);
      float c = relu_(acc[1][2*j]   * scv + shv);
      float d = relu_(acc[1][2*j+1] * scv + shv);
      tt[oc][py*12 + j] = fmaxf(fmaxf(a, b), fmaxf(c, d));
    }
  }
  __syncthreads();
  unsigned int* dst = pool1t + (size_t)img * 1728;
  for (int i = tid; i < 1728; i += 256) {
    const int pix = i / 12, d = i - pix*12;
    const int oc0 = 2*d, oc1 = 2*d + 1;
    const float v0 = (oc0 < 20) ? tt[oc0][pix] : 0.f;
    const float v1 = (oc1 < 20) ? tt[oc1][pix] : 0.f;
    dst[i] = pack_bf16x2(v0, v1);
  }
}

// ---- weight prep: c2w OIHW fp32 -> Wb[cc 0..75][n 0..63][j 0..7] bf16 ----
// k-index: k = khw*24 + ic  (khw = kh*5+kw, ic padded to 24); chunk cc = k/8.
__global__ __launch_bounds__(256) void k_wprep(
    const float* __restrict__ w, unsigned short* __restrict__ wb)
{
  const int idx = blockIdx.x * 256 + threadIdx.x;    // 38912 total
  const int cc = idx >> 9;
  const int rem = idx & 511;
  const int n = rem >> 3, j = rem & 7;
  float v = 0.f;
  if (cc < 75 && n < 50) {
    const int khw = cc / 3, icg = cc - khw*3;
    const int ic = icg*8 + j;
    if (ic < 20) {
      const int kh = khw / 5, kw = khw - kh*5;
      v = w[((n*20 + ic)*5 + kh)*5 + kw];
    }
  }
  __hip_bfloat16 h = __float2bfloat16(v);
  unsigned short u; __builtin_memcpy(&u, &h, 2);
  wb[idx] = u;
}

// ---- conv2 as implicit-GEMM MFMA: wave = 1 image (M=64 px), N=64(50), K=608 ----
__global__ __launch_bounds__(256) void k_conv2_mfma(
    const unsigned int* __restrict__ pool1t, const unsigned short* __restrict__ wb,
    const float* __restrict__ bias, float* __restrict__ c2raw,
    float* __restrict__ part)
{
  __shared__ alignas(16) unsigned int in4[6912];     // 4 imgs * 6912 B
  __shared__ float sred[4][64], qred[4][64];
  const int tid = threadIdx.x, blk = blockIdx.x;
  const unsigned int* src = pool1t + (size_t)blk * 6912;
  for (int i = tid; i < 1728; i += 256)
    ((uint4*)in4)[i] = ((const uint4*)src)[i];
  __syncthreads();

  const int wave = tid >> 6, lane = tid & 63;
  const int lo = lane & 15, hi = lane >> 4;
  const char* ibase = (const char*)in4 + wave * 6912;

  int pixb[4];
  #pragma unroll
  for (int a = 0; a < 4; ++a) { const int m = a*16 + lo; pixb[a] = (m >> 3) * 12 + (m & 7); }
  float bval[4];
  #pragma unroll
  for (int nf = 0; nf < 4; ++nf) { const int n = nf*16 + lo; bval[nf] = (n < 50) ? bias[n] : 0.f; }

  float4v acc[4][4];
  #pragma unroll
  for (int a = 0; a < 4; ++a)
    #pragma unroll
    for (int nf = 0; nf < 4; ++nf) acc[a][nf] = (float4v){0.f, 0.f, 0.f, 0.f};

  for (int s = 0; s < 19; ++s) {
    const int cc = s*4 + hi;                 // 0..75 (75 = zero weight chunk)
    const int cca = cc > 74 ? 74 : cc;       // clamp A-read in range (W=0 there)
    const int khw = cca / 3, icg = cca - khw*3;
    const int kh = khw / 5, kw = khw - kh*5;
    const int khoff = kh*12 + kw;
    short8v av[4];
    #pragma unroll
    for (int am = 0; am < 4; ++am)
      av[am] = *(const short8v*)(ibase + (size_t)(pixb[am] + khoff)*48 + icg*16);
    short8v bv[4];
    const unsigned short* wrow = wb + (size_t)cc*512 + lo*8;
    #pragma unroll
    for (int nf = 0; nf < 4; ++nf)
      bv[nf] = *(const short8v*)(wrow + nf*128);
    #pragma unroll
    for (int am = 0; am < 4; ++am)
      #pragma unroll
      for (int nf = 0; nf < 4; ++nf)
        acc[am][nf] = __builtin_amdgcn_mfma_f32_16x16x32_bf16(av[am], bv[nf], acc[am][nf], 0, 0, 0);
  }

  const int img = blk*4 + wave;
  #pragma unroll
  for (int nf = 0; nf < 4; ++nf) {
    const int n = nf*16 + lo;
    float sv = 0.f, qv = 0.f;
    #pragma unroll
    for (int am = 0; am < 4; ++am) {
      float4v v = acc[am][nf];
      #pragma unroll
      for (int r = 0; r < 4; ++r) v[r] += bval[nf];
      #pragma unroll
      for (int r = 0; r < 4; ++r) { sv += v[r]; qv += v[r]*v[r]; }
      if (n < 50) {
        float4 o; o.x = v[0]; o.y = v[1]; o.z = v[2]; o.w = v[3];
        *(float4*)(c2raw + (size_t)img*3200 + n*64 + am*16 + hi*4) = o;
      }
    }
    sv += __shfl_down(sv, 32); qv += __shfl_down(qv, 32);
    sv += __shfl_down(sv, 16); qv += __shfl_down(qv, 16);
    if (hi == 0) { sred[wave][nf*16 + lo] = sv; qred[wave][nf*16 + lo] = qv; }
  }
  __syncthreads();
  if (tid < 100) {
    const int ch = tid < 50 ? tid : tid - 50;
    float t = 0.f;
    if (tid < 50) {
      #pragma unroll
      for (int w2 = 0; w2 < 4; ++w2) t += sred[w2][ch];
      part[(size_t)blk*100 + ch] = t;
    } else {
      #pragma unroll
      for (int w2 = 0; w2 < 4; ++w2) t += qred[w2][ch];
      part[(size_t)blk*100 + 50 + ch] = t;
    }
  }
}

// ---- BN finalize: reduce per-block partials (double), emit scale/shift ----
__global__ __launch_bounds__(256) void k_bn_fin(
    const float* __restrict__ part, int nblk, int nch, float N,
    const float* __restrict__ g, const float* __restrict__ b,
    float* __restrict__ out)
{
  __shared__ double rd[4][2];
  const int tid = threadIdx.x, ch = blockIdx.x;
  const int lane = tid & 63, wid = tid >> 6;
  double s = 0.0, q = 0.0;
  for (int i = tid; i < nblk; i += 256) {
    s += (double)part[(size_t)i*2*nch + ch];
    q += (double)part[(size_t)i*2*nch + nch + ch];
  }
  #pragma unroll
  for (int off = 32; off > 0; off >>= 1) { s += __shfl_down(s, off); q += __shfl_down(q, off); }
  if (lane == 0) { rd[wid][0] = s; rd[wid][1] = q; }
  __syncthreads();
  if (tid == 0) {
    double S = rd[0][0] + rd[1][0] + rd[2][0] + rd[3][0];
    double Q = rd[0][1] + rd[1][1] + rd[2][1] + rd[3][1];
    double mean = S / (double)N;
    double var  = Q / (double)N - mean * mean;
    if (var < 0.0) var = 0.0;
    float scv = (float)((double)g[ch] / sqrt(var + 1e-5));
    out[ch]       = scv;
    out[nch + ch] = b[ch] - (float)mean * scv;
  }
}

// ---- BN2 + ReLU + 2x2 maxpool: (B,50,8,8) -> pool2 (B,800) ----
__global__ __launch_bounds__(256) void k_bnpool2(
    const float* __restrict__ raw, const float* __restrict__ bn2,
    float* __restrict__ pool2)
{
  const int gid = blockIdx.x * 256 + threadIdx.x;
  const int b = gid / 800, r = gid % 800;
  const int oc = r >> 4, p = r & 15, py = p >> 2, px = p & 3;
  const float sc = bn2[oc], sh = bn2[50 + oc];
  const float* base = raw + (size_t)b*3200 + oc*64 + py*16 + px*2;
  float v0 = relu_(base[0]*sc + sh);
  float v1 = relu_(base[1]*sc + sh);
  float v2 = relu_(base[8]*sc + sh);
  float v3 = relu_(base[9]*sc + sh);
  pool2[gid] = fmaxf(fmaxf(v0, v1), fmaxf(v2, v3));
}

// ---- fc1: (B,800)x(10,800)^T + bias, + per-feature partial stats ----
__global__ __launch_bounds__(256) void k_fc1(
    const float* __restrict__ pool2, const float* __restrict__ w,
    const float* __restrict__ bias, float* __restrict__ h_raw,
    float* __restrict__ part)
{
  __shared__ alignas(16) float wl[8000];
  __shared__ float bsh[10];
  __shared__ float red[4][20];
  const int tid = threadIdx.x;
  for (int i = tid; i < 2000; i += 256)
    ((float4*)wl)[i] = ((const float4*)w)[i];
  if (tid < 10) bsh[tid] = bias[tid];
  __syncthreads();
  const int b = blockIdx.x * 256 + tid;
  const float* xr = pool2 + (size_t)b * 800;
  float acc[10];
  #pragma unroll
  for (int f = 0; f < 10; ++f) acc[f] = bsh[f];
  for (int k = 0; k < 800; k += 4) {
    const float4 v = *(const float4*)(xr + k);
    #pragma unroll
    for (int f = 0; f < 10; ++f) {
      const float4 wv = *(const float4*)(wl + f*800 + k);
      acc[f] += v.x*wv.x + v.y*wv.y + v.z*wv.z + v.w*wv.w;
    }
  }
  #pragma unroll
  for (int f = 0; f < 10; ++f) h_raw[(size_t)b*10 + f] = acc[f];
  const int lane = tid & 63, wid = tid >> 6;
  #pragma unroll
  for (int f = 0; f < 10; ++f) {
    float sv = acc[f], qv = acc[f]*acc[f];
    #pragma unroll
    for (int off = 32; off > 0; off >>= 1) { sv += __shfl_down(sv, off); qv += __shfl_down(qv, off); }
    if (lane == 0) { red[wid][f] = sv; red[wid][10+f] = qv; }
  }
  __syncthreads();
  if (tid < 20)
    part[(size_t)blockIdx.x*20 + tid] = red[0][tid] + red[1][tid] + red[2][tid] + red[3][tid];
}

// ---- BN3+ReLU on h, theta logits -> sigmoid p, tree walk -> mu ----
__global__ __launch_bounds__(256) void k_theta_mu(
    const float* __restrict__ h_raw, const float* __restrict__ bn3,
    const float* __restrict__ tw, const float* __restrict__ tb,
    float* __restrict__ mu)
{
  __shared__ float twl[2550];
  __shared__ float hl[10];
  __shared__ float pl[256];
  const int tid = threadIdx.x, b = blockIdx.x;
  for (int i = tid; i < 2550; i += 256) twl[i] = tw[i];
  if (tid < 10) {
    float v = h_raw[(size_t)b*10 + tid] * bn3[tid] + bn3[10 + tid];
    hl[tid] = relu_(v);
  }
  __syncthreads();
  if (tid < 255) {
    float d = tb[tid];
    #pragma unroll
    for (int f = 0; f < 10; ++f) d += hl[f] * twl[tid*10 + f];
    pl[tid] = 1.f / (1.f + expf(-d));
  }
  __syncthreads();
  float m = 1.f; int idx = 0;
  #pragma unroll
  for (int k = 0; k < 8; ++k) {
    const int dir = (tid >> (7 - k)) & 1;
    const float pv = pl[idx];
    m *= dir ? pv : (1.f - pv);
    idx += dir ? (1 << (7 - k)) : 1;
  }
  mu[(size_t)b*256 + tid] = m;
}

// ---- S_raw[l,c] = sum over samples of class c of mu[b,l] ----
__global__ __launch_bounds__(256) void k_S(
    const float* __restrict__ mu, const int* __restrict__ y,
    float* __restrict__ S)
{
  const int tid = threadIdx.x;
  const int b0 = blockIdx.x * 64;
  float acc[10];
  #pragma unroll
  for (int c = 0; c < 10; ++c) acc[c] = 0.f;
  for (int s = 0; s < 64; ++s) {
    const int b = b0 + s;
    const float m = mu[(size_t)b*256 + tid];
    const int c = y[b];
    #pragma unroll
    for (int cc = 0; cc < 10; ++cc) acc[cc] += (c == cc) ? m : 0.f;
  }
  #pragma unroll
  for (int cc = 0; cc < 10; ++cc) atomicAdd(&S[tid*10 + cc], acc[cc]);
}

// ---- pi EM update (tiny, one block; thread = leaf) ----
__global__ __launch_bounds__(256) void k_pi(
    const float* __restrict__ pi, const float* __restrict__ S,
    float* __restrict__ pi_new)
{
  __shared__ float pin[2560];
  __shared__ float Pp[10];
  const int t = threadIdx.x;
  float row[10]; float rs = 0.f;
  #pragma unroll
  for (int c = 0; c < 10; ++c) { row[c] = pi[t*10 + c]; rs += row[c]; }
  #pragma unroll
  for (int c = 0; c < 10; ++c) { row[c] /= rs; pin[t*10 + c] = row[c]; }
  __syncthreads();
  if (t < 10) {
    float s = 0.f;
    for (int l = 0; l < 256; ++l) s += pin[l*10 + t];
    Pp[t] = s / 256.f;
  }
  __syncthreads();
  float hs = 0.f; float ph[10];
  #pragma unroll
  for (int c = 0; c < 10; ++c) {
    const float Sv = S[t*10 + c] / Pp[c];
    ph[c] = row[c] * Sv;
    hs += ph[c];
  }
  #pragma unroll
  for (int c = 0; c < 10; ++c) pi_new[t*10 + c] = ph[c] / hs;
}

// ---- out = log(mu @ pi_new) ----
__global__ __launch_bounds__(256) void k_out(
    const float* __restrict__ mu, const float* __restrict__ pn,
    float* __restrict__ out)
{
  __shared__ float pl[2560];
  const int tid = threadIdx.x;
  for (int i = tid; i < 2560; i += 256) pl[i] = pn[i];
  __syncthreads();
  const int gid = blockIdx.x * 256 + tid;
  const int b = gid / 10, c = gid % 10;
  const float* mr = mu + (size_t)b * 256;
  float acc = 0.f;
  for (int l = 0; l < 256; ++l) acc += mr[l] * pl[l*10 + c];
  out[gid] = logf(acc);
}

extern "C" void kernel_launch(void* const* d_in, const int* in_sizes, int n_in,
                              void* d_out, int out_size, void* d_ws, size_t ws_size,
                              hipStream_t stream)
{
  const float* x   = (const float*)d_in[0];
  const int*   y   = (const int*)  d_in[1];
  const float* c1w = (const float*)d_in[2];
  const float* c1b = (const float*)d_in[3];
  const float* c2w = (const float*)d_in[4];
  const float* c2b = (const float*)d_in[5];
  const float* g1  = (const float*)d_in[6];
  const float* be1 = (const float*)d_in[7];
  const float* g2  = (const float*)d_in[8];
  const float* be2 = (const float*)d_in[9];
  const float* fw  = (const float*)d_in[10];
  const float* fb  = (const float*)d_in[11];
  const float* g3  = (const float*)d_in[12];
  const float* be3 = (const float*)d_in[13];
  const float* thw = (const float*)d_in[14];
  const float* thb = (const float*)d_in[15];
  const float* pi  = (const float*)d_in[16];
  float* ws  = (float*)d_ws;
  float* out = (float*)d_out;

  unsigned int*   pool1t = (unsigned int*)(ws + F_POOL1T);
  float*          c2raw  = ws + F_C2;
  float*          part1  = ws + F_PART1;
  float*          part2  = ws + F_PART2;
  float*          part3  = ws + F_PART3;
  float*          bn1    = ws + F_BN1;
  float*          bn2    = ws + F_BN2;
  float*          bn3    = ws + F_BN3;
  float*          sraw   = ws + F_SRAW;
  float*          pinew  = ws + F_PINEW;
  unsigned short* wbuf   = (unsigned short*)(ws + F_WB);
  float*          pool2  = ws + F_POOL2;
  float*          hraw   = ws + F_HRAW;
  float*          muB    = ws + F_MU;

  hipMemsetAsync(sraw, 0, 2560 * sizeof(float), stream);

  k_wprep<<<152, 256, 0, stream>>>(c2w, wbuf);
  k_conv1_stats<<<8192, 256, 0, stream>>>(x, c1w, c1b, part1);
  k_bn_fin<<<20, 256, 0, stream>>>(part1, 8192, 20, 8192.f * 576.f, g1, be1, bn1);
  k_conv1_pool<<<8192, 256, 0, stream>>>(x, c1w, c1b, bn1, pool1t);
  k_conv2_mfma<<<2048, 256, 0, stream>>>(pool1t, wbuf, c2b, c2raw, part2);
  k_bn_fin<<<50, 256, 0, stream>>>(part2, 2048, 50, 8192.f * 64.f, g2, be2, bn2);
  k_bnpool2<<<25600, 256, 0, stream>>>(c2raw, bn2, pool2);
  k_fc1<<<32, 256, 0, stream>>>(pool2, fw, fb, hraw, part3);
  k_bn_fin<<<10, 256, 0, stream>>>(part3, 32, 10, 8192.f, g3, be3, bn3);
  k_theta_mu<<<8192, 256, 0, stream>>>(hraw, bn3, thw, thb, muB);
  k_S<<<128, 256, 0, stream>>>(muB, y, sraw);
  k_pi<<<1, 256, 0, stream>>>(pi, sraw, pinew);
  k_out<<<320, 256, 0, stream>>>(muB, pinew, out);
}

// Round 3
// 360.662 us; speedup vs baseline: 2.7413x; 1.2259x over previous
//
#include <hip/hip_runtime.h>
#include <hip/hip_bf16.h>
#include <math.h>

typedef __attribute__((ext_vector_type(8))) short short8v;
typedef __attribute__((ext_vector_type(4))) float float4v;

// ---------------- workspace layout (float/dword offsets) ----------------
static const size_t F_RAWP1 = 0;               // fp32 ch-last pooled raw conv1 [8192][144][24] = 28,311,552
static const size_t F_C2P   = 28311552;        // fp32 pooled raw conv2 [8192][800] = 6,553,600
static const size_t F_PART1 = 34865152;        // 8192*40
static const size_t F_PART2 = 35192832;        // 2048*100
static const size_t F_PART3 = 35397632;        // 32*20
static const size_t F_BN1   = 35398272;        // 40
static const size_t F_BN2   = 35398312;        // 100
static const size_t F_BN3   = 35398412;        // 20
static const size_t F_SRAW  = 35398432;        // 2560
static const size_t F_PINEW = 35400992;        // 2560
static const size_t F_WB    = 35403552;        // 19456 dwords (76*64*8 bf16)
// overlays in rawp1 region (dead after conv2):
static const size_t F_POOL2 = 0;               // 8192*800
static const size_t F_HRAW  = 6553600;         // 8192*10
static const size_t F_MU    = 6635520;         // 8192*256

__device__ __forceinline__ float relu_(float v) { return v > 0.f ? v : 0.f; }

__device__ __forceinline__ unsigned int pack_bf16x2(float a, float b) {
  __hip_bfloat16 ha = __float2bfloat16(a), hb = __float2bfloat16(b);
  unsigned short ua, ub;
  __builtin_memcpy(&ua, &ha, 2); __builtin_memcpy(&ub, &hb, 2);
  return ((unsigned int)ub << 16) | ua;
}

// ---- fused conv1: raw conv + BN1 partial stats + sign-aware 2x2 pool ----
// writes pooled RAW (pre-BN) channel-last fp32 [img][144 px][24 ch] (pad=0)
__global__ __launch_bounds__(512) void k_conv1_fused(
    const float* __restrict__ x, const float* __restrict__ w,
    const float* __restrict__ bias, const float* __restrict__ g1,
    float* __restrict__ rawp1, float* __restrict__ part)
{
  __shared__ alignas(16) float xs[784];
  __shared__ float wsh[500];
  __shared__ float bsh[20], sgn[20];
  __shared__ float ssum[20], ssq[20];
  __shared__ float tt2[24][20][12];          // horizontally-pooled raw
  const int tid = threadIdx.x;
  const int img = blockIdx.x;
  const float* xp = x + (size_t)img * 784;
  for (int i = tid; i < 784; i += 512) xs[i] = xp[i];
  for (int i = tid; i < 500; i += 512) wsh[i] = w[i];
  if (tid < 20) {
    bsh[tid] = bias[tid];
    sgn[tid] = (g1[tid] >= 0.f) ? 1.f : -1.f;
    ssum[tid] = 0.f; ssq[tid] = 0.f;
  }
  __syncthreads();
  if (tid < 480) {
    const int oy = tid / 20, oc = tid % 20;  // oy-major: distinct oc per lane -> no atomic collision in-wave
    float acc[24];
    const float bv = bsh[oc];
    #pragma unroll
    for (int j = 0; j < 24; ++j) acc[j] = bv;
    #pragma unroll
    for (int kh = 0; kh < 5; ++kh) {
      const float* row = &xs[(oy + kh) * 28];
      float r[28];
      #pragma unroll
      for (int j = 0; j < 7; ++j) {
        const float4 v = *(const float4*)(row + 4 * j);
        r[4*j] = v.x; r[4*j+1] = v.y; r[4*j+2] = v.z; r[4*j+3] = v.w;
      }
      #pragma unroll
      for (int kw = 0; kw < 5; ++kw) {
        const float wv = wsh[oc*25 + kh*5 + kw];
        #pragma unroll
        for (int j = 0; j < 24; ++j) acc[j] += r[j + kw] * wv;
      }
    }
    float s = 0.f, q = 0.f;
    #pragma unroll
    for (int j = 0; j < 24; ++j) { s += acc[j]; q += acc[j] * acc[j]; }
    atomicAdd(&ssum[oc], s);
    atomicAdd(&ssq[oc], q);
    const bool mx = sgn[oc] >= 0.f;
    #pragma unroll
    for (int j = 0; j < 12; ++j)
      tt2[oy][oc][j] = mx ? fmaxf(acc[2*j], acc[2*j+1]) : fminf(acc[2*j], acc[2*j+1]);
  }
  __syncthreads();
  float* dst = rawp1 + (size_t)img * 3456;
  for (int i = tid; i < 3456; i += 512) {
    const int pix = i / 24, ch = i - pix*24;
    float v = 0.f;
    if (ch < 20) {
      const int py = pix / 12, px = pix - py*12;
      const float a = tt2[2*py][ch][px], b = tt2[2*py+1][ch][px];
      v = (sgn[ch] >= 0.f) ? fmaxf(a, b) : fminf(a, b);
    }
    dst[i] = v;
  }
  if (tid < 20) {
    part[(size_t)img*40 + tid]      = ssum[tid];
    part[(size_t)img*40 + 20 + tid] = ssq[tid];
  }
}

// ---- weight prep: c2w OIHW fp32 -> Wb[cc 0..75][n 0..63][j 0..7] bf16 ----
__global__ __launch_bounds__(256) void k_wprep(
    const float* __restrict__ w, unsigned short* __restrict__ wb)
{
  const int idx = blockIdx.x * 256 + threadIdx.x;    // 38912 total
  const int cc = idx >> 9;
  const int rem = idx & 511;
  const int n = rem >> 3, j = rem & 7;
  float v = 0.f;
  if (cc < 75 && n < 50) {
    const int khw = cc / 3, icg = cc - khw*3;
    const int ic = icg*8 + j;
    if (ic < 20) {
      const int kh = khw / 5, kw = khw - kh*5;
      v = w[((n*20 + ic)*5 + kh)*5 + kw];
    }
  }
  __hip_bfloat16 h = __float2bfloat16(v);
  unsigned short u; __builtin_memcpy(&u, &h, 2);
  wb[idx] = u;
}

// ---- conv2 implicit-GEMM MFMA; staging applies BN1+ReLU+bf16 pack;
//      epilogue: BN2 partial stats + in-register sign-aware 2x2 pool ----
__global__ __launch_bounds__(256) void k_conv2_mfma(
    const float* __restrict__ rawp1, const unsigned short* __restrict__ wb,
    const float* __restrict__ bn1, const float* __restrict__ bias2,
    const float* __restrict__ g2, float* __restrict__ c2p,
    float* __restrict__ part)
{
  __shared__ alignas(16) unsigned int in4[6912];     // 4 imgs, bf16 ch-last [144][24]
  __shared__ float sred[4][64], qred[4][64];
  __shared__ float sc1[20], sh1[20];
  const int tid = threadIdx.x, blk = blockIdx.x;
  if (tid < 20) { sc1[tid] = bn1[tid]; sh1[tid] = bn1[20 + tid]; }
  __syncthreads();
  const float* src = rawp1 + (size_t)blk * 13824;
  for (int d = tid; d < 6912; d += 256) {
    const int il = d / 1728, r = d - il*1728;
    const int pix = r / 12, chp = r - pix*12;
    unsigned int pv = 0u;
    if (chp < 10) {
      const float2 v = *(const float2*)(src + (size_t)il*3456 + pix*24 + 2*chp);
      const float a = relu_(v.x * sc1[2*chp]   + sh1[2*chp]);
      const float b = relu_(v.y * sc1[2*chp+1] + sh1[2*chp+1]);
      pv = pack_bf16x2(a, b);
    }
    in4[d] = pv;
  }
  __syncthreads();

  const int wave = tid >> 6, lane = tid & 63;
  const int lo = lane & 15, hi = lane >> 4;
  const char* ibase = (const char*)in4 + wave * 6912;

  int pixb[4];
  #pragma unroll
  for (int a = 0; a < 4; ++a) { const int m = a*16 + lo; pixb[a] = (m >> 3) * 12 + (m & 7); }
  float bval[4]; bool gpos[4];
  #pragma unroll
  for (int nf = 0; nf < 4; ++nf) {
    const int n = nf*16 + lo;
    bval[nf] = (n < 50) ? bias2[n] : 0.f;
    gpos[nf] = (n < 50) ? (g2[n] >= 0.f) : true;
  }

  float4v acc[4][4];
  #pragma unroll
  for (int a = 0; a < 4; ++a)
    #pragma unroll
    for (int nf = 0; nf < 4; ++nf) acc[a][nf] = (float4v){0.f, 0.f, 0.f, 0.f};

  for (int s = 0; s < 19; ++s) {
    const int cc = s*4 + hi;                 // 0..75 (75 = zero weight chunk)
    const int cca = cc > 74 ? 74 : cc;
    const int khw = cca / 3, icg = cca - khw*3;
    const int kh = khw / 5, kw = khw - kh*5;
    const int khoff = kh*12 + kw;
    short8v av[4];
    #pragma unroll
    for (int am = 0; am < 4; ++am)
      av[am] = *(const short8v*)(ibase + (size_t)(pixb[am] + khoff)*48 + icg*16);
    short8v bv[4];
    const unsigned short* wrow = wb + (size_t)cc*512 + lo*8;
    #pragma unroll
    for (int nf = 0; nf < 4; ++nf)
      bv[nf] = *(const short8v*)(wrow + nf*128);
    #pragma unroll
    for (int am = 0; am < 4; ++am)
      #pragma unroll
      for (int nf = 0; nf < 4; ++nf)
        acc[am][nf] = __builtin_amdgcn_mfma_f32_16x16x32_bf16(av[am], bv[nf], acc[am][nf], 0, 0, 0);
  }

  const int img = blk*4 + wave;
  #pragma unroll
  for (int nf = 0; nf < 4; ++nf) {
    const int n = nf*16 + lo;
    float sv = 0.f, qv = 0.f;
    #pragma unroll
    for (int am = 0; am < 4; ++am) {
      float4v v = acc[am][nf];
      #pragma unroll
      for (int r = 0; r < 4; ++r) v[r] += bval[nf];
      #pragma unroll
      for (int r = 0; r < 4; ++r) { sv += v[r]; qv += v[r]*v[r]; }
      // in-register 2x2 pool of RAW values (sign-aware):
      // lane(hi,am): regs = one row oy=2*am+(hi>>1), ox = (hi&1)*4 + r
      float h0 = gpos[nf] ? fmaxf(v[0], v[1]) : fminf(v[0], v[1]);
      float h1 = gpos[nf] ? fmaxf(v[2], v[3]) : fminf(v[2], v[3]);
      const float o0 = __shfl_xor(h0, 32);
      const float o1 = __shfl_xor(h1, 32);
      h0 = gpos[nf] ? fmaxf(h0, o0) : fminf(h0, o0);
      h1 = gpos[nf] ? fmaxf(h1, o1) : fminf(h1, o1);
      if (hi < 2 && n < 50) {
        // pooled (py=am, px = hi*2 + {0,1}) -> c2p[img][n][py][px]
        float2 o; o.x = h0; o.y = h1;
        *(float2*)(c2p + (size_t)img*800 + n*16 + am*4 + hi*2) = o;
      }
    }
    sv += __shfl_down(sv, 32); qv += __shfl_down(qv, 32);
    sv += __shfl_down(sv, 16); qv += __shfl_down(qv, 16);
    if (hi == 0) { sred[wave][nf*16 + lo] = sv; qred[wave][nf*16 + lo] = qv; }
  }
  __syncthreads();
  if (tid < 100) {
    const int ch = tid < 50 ? tid : tid - 50;
    float t = 0.f;
    if (tid < 50) {
      #pragma unroll
      for (int w2 = 0; w2 < 4; ++w2) t += sred[w2][ch];
      part[(size_t)blk*100 + ch] = t;
    } else {
      #pragma unroll
      for (int w2 = 0; w2 < 4; ++w2) t += qred[w2][ch];
      part[(size_t)blk*100 + 50 + ch] = t;
    }
  }
}

// ---- BN finalize: reduce per-block partials (double), emit scale/shift ----
__global__ __launch_bounds__(256) void k_bn_fin(
    const float* __restrict__ part, int nblk, int nch, float N,
    const float* __restrict__ g, const float* __restrict__ b,
    float* __restrict__ out)
{
  __shared__ double rd[4][2];
  const int tid = threadIdx.x, ch = blockIdx.x;
  const int lane = tid & 63, wid = tid >> 6;
  double s = 0.0, q = 0.0;
  for (int i = tid; i < nblk; i += 256) {
    s += (double)part[(size_t)i*2*nch + ch];
    q += (double)part[(size_t)i*2*nch + nch + ch];
  }
  #pragma unroll
  for (int off = 32; off > 0; off >>= 1) { s += __shfl_down(s, off); q += __shfl_down(q, off); }
  if (lane == 0) { rd[wid][0] = s; rd[wid][1] = q; }
  __syncthreads();
  if (tid == 0) {
    double S = rd[0][0] + rd[1][0] + rd[2][0] + rd[3][0];
    double Q = rd[0][1] + rd[1][1] + rd[2][1] + rd[3][1];
    double mean = S / (double)N;
    double var  = Q / (double)N - mean * mean;
    if (var < 0.0) var = 0.0;
    float scv = (float)((double)g[ch] / sqrt(var + 1e-5));
    out[ch]       = scv;
    out[nch + ch] = b[ch] - (float)mean * scv;
  }
}

// ---- BN2+ReLU on pooled raw: c2p (B,800) -> pool2 (B,800), float4 ----
__global__ __launch_bounds__(256) void k_bnapply(
    const float* __restrict__ c2p, const float* __restrict__ bn2,
    float* __restrict__ pool2)
{
  const int g4 = blockIdx.x * 256 + threadIdx.x;    // 1,638,400 float4s
  const int r4 = (g4 * 4) % 800;
  const int oc = r4 >> 4;
  const float sc = bn2[oc], sh = bn2[50 + oc];
  float4 v = ((const float4*)c2p)[g4];
  v.x = relu_(v.x*sc + sh); v.y = relu_(v.y*sc + sh);
  v.z = relu_(v.z*sc + sh); v.w = relu_(v.w*sc + sh);
  ((float4*)pool2)[g4] = v;
}

// ---- fc1: (B,800)x(10,800)^T + bias, + per-feature partial stats ----
__global__ __launch_bounds__(256) void k_fc1(
    const float* __restrict__ pool2, const float* __restrict__ w,
    const float* __restrict__ bias, float* __restrict__ h_raw,
    float* __restrict__ part)
{
  __shared__ alignas(16) float wl[8000];
  __shared__ float bsh[10];
  __shared__ float red[4][20];
  const int tid = threadIdx.x;
  for (int i = tid; i < 2000; i += 256)
    ((float4*)wl)[i] = ((const float4*)w)[i];
  if (tid < 10) bsh[tid] = bias[tid];
  __syncthreads();
  const int b = blockIdx.x * 256 + tid;
  const float* xr = pool2 + (size_t)b * 800;
  float acc[10];
  #pragma unroll
  for (int f = 0; f < 10; ++f) acc[f] = bsh[f];
  for (int k = 0; k < 800; k += 4) {
    const float4 v = *(const float4*)(xr + k);
    #pragma unroll
    for (int f = 0; f < 10; ++f) {
      const float4 wv = *(const float4*)(wl + f*800 + k);
      acc[f] += v.x*wv.x + v.y*wv.y + v.z*wv.z + v.w*wv.w;
    }
  }
  #pragma unroll
  for (int f = 0; f < 10; ++f) h_raw[(size_t)b*10 + f] = acc[f];
  const int lane = tid & 63, wid = tid >> 6;
  #pragma unroll
  for (int f = 0; f < 10; ++f) {
    float sv = acc[f], qv = acc[f]*acc[f];
    #pragma unroll
    for (int off = 32; off > 0; off >>= 1) { sv += __shfl_down(sv, off); qv += __shfl_down(qv, off); }
    if (lane == 0) { red[wid][f] = sv; red[wid][10+f] = qv; }
  }
  __syncthreads();
  if (tid < 20)
    part[(size_t)blockIdx.x*20 + tid] = red[0][tid] + red[1][tid] + red[2][tid] + red[3][tid];
}

// ---- BN3+ReLU on h, theta logits -> sigmoid p, tree walk -> mu ----
__global__ __launch_bounds__(256) void k_theta_mu(
    const float* __restrict__ h_raw, const float* __restrict__ bn3,
    const float* __restrict__ tw, const float* __restrict__ tb,
    float* __restrict__ mu)
{
  __shared__ float twl[2550];
  __shared__ float hl[10];
  __shared__ float pl[256];
  const int tid = threadIdx.x, b = blockIdx.x;
  for (int i = tid; i < 2550; i += 256) twl[i] = tw[i];
  if (tid < 10) {
    float v = h_raw[(size_t)b*10 + tid] * bn3[tid] + bn3[10 + tid];
    hl[tid] = relu_(v);
  }
  __syncthreads();
  if (tid < 255) {
    float d = tb[tid];
    #pragma unroll
    for (int f = 0; f < 10; ++f) d += hl[f] * twl[tid*10 + f];
    pl[tid] = 1.f / (1.f + expf(-d));
  }
  __syncthreads();
  float m = 1.f; int idx = 0;
  #pragma unroll
  for (int k = 0; k < 8; ++k) {
    const int dir = (tid >> (7 - k)) & 1;
    const float pv = pl[idx];
    m *= dir ? pv : (1.f - pv);
    idx += dir ? (1 << (7 - k)) : 1;
  }
  mu[(size_t)b*256 + tid] = m;
}

// ---- S_raw[l,c] = sum over samples of class c of mu[b,l] ----
__global__ __launch_bounds__(256) void k_S(
    const float* __restrict__ mu, const int* __restrict__ y,
    float* __restrict__ S)
{
  const int tid = threadIdx.x;
  const int b0 = blockIdx.x * 64;
  float acc[10];
  #pragma unroll
  for (int c = 0; c < 10; ++c) acc[c] = 0.f;
  for (int s = 0; s < 64; ++s) {
    const int b = b0 + s;
    const float m = mu[(size_t)b*256 + tid];
    const int c = y[b];
    #pragma unroll
    for (int cc = 0; cc < 10; ++cc) acc[cc] += (c == cc) ? m : 0.f;
  }
  #pragma unroll
  for (int cc = 0; cc < 10; ++cc) atomicAdd(&S[tid*10 + cc], acc[cc]);
}

// ---- pi EM update (tiny, one block; thread = leaf) ----
__global__ __launch_bounds__(256) void k_pi(
    const float* __restrict__ pi, const float* __restrict__ S,
    float* __restrict__ pi_new)
{
  __shared__ float pin[2560];
  __shared__ float Pp[10];
  const int t = threadIdx.x;
  float row[10]; float rs = 0.f;
  #pragma unroll
  for (int c = 0; c < 10; ++c) { row[c] = pi[t*10 + c]; rs += row[c]; }
  #pragma unroll
  for (int c = 0; c < 10; ++c) { row[c] /= rs; pin[t*10 + c] = row[c]; }
  __syncthreads();
  if (t < 10) {
    float s = 0.f;
    for (int l = 0; l < 256; ++l) s += pin[l*10 + t];
    Pp[t] = s / 256.f;
  }
  __syncthreads();
  float hs = 0.f; float ph[10];
  #pragma unroll
  for (int c = 0; c < 10; ++c) {
    const float Sv = S[t*10 + c] / Pp[c];
    ph[c] = row[c] * Sv;
    hs += ph[c];
  }
  #pragma unroll
  for (int c = 0; c < 10; ++c) pi_new[t*10 + c] = ph[c] / hs;
}

// ---- out = log(mu @ pi_new) ----
__global__ __launch_bounds__(256) void k_out(
    const float* __restrict__ mu, const float* __restrict__ pn,
    float* __restrict__ out)
{
  __shared__ float pl[2560];
  const int tid = threadIdx.x;
  for (int i = tid; i < 2560; i += 256) pl[i] = pn[i];
  __syncthreads();
  const int gid = blockIdx.x * 256 + tid;
  const int b = gid / 10, c = gid % 10;
  const float* mr = mu + (size_t)b * 256;
  float acc = 0.f;
  for (int l = 0; l < 256; ++l) acc += mr[l] * pl[l*10 + c];
  out[gid] = logf(acc);
}

extern "C" void kernel_launch(void* const* d_in, const int* in_sizes, int n_in,
                              void* d_out, int out_size, void* d_ws, size_t ws_size,
                              hipStream_t stream)
{
  const float* x   = (const float*)d_in[0];
  const int*   y   = (const int*)  d_in[1];
  const float* c1w = (const float*)d_in[2];
  const float* c1b = (const float*)d_in[3];
  const float* c2w = (const float*)d_in[4];
  const float* c2b = (const float*)d_in[5];
  const float* g1  = (const float*)d_in[6];
  const float* be1 = (const float*)d_in[7];
  const float* g2  = (const float*)d_in[8];
  const float* be2 = (const float*)d_in[9];
  const float* fw  = (const float*)d_in[10];
  const float* fb  = (const float*)d_in[11];
  const float* g3  = (const float*)d_in[12];
  const float* be3 = (const float*)d_in[13];
  const float* thw = (const float*)d_in[14];
  const float* thb = (const float*)d_in[15];
  const float* pi  = (const float*)d_in[16];
  float* ws  = (float*)d_ws;
  float* out = (float*)d_out;

  float*          rawp1 = ws + F_RAWP1;
  float*          c2p   = ws + F_C2P;
  float*          part1 = ws + F_PART1;
  float*          part2 = ws + F_PART2;
  float*          part3 = ws + F_PART3;
  float*          bn1   = ws + F_BN1;
  float*          bn2   = ws + F_BN2;
  float*          bn3   = ws + F_BN3;
  float*          sraw  = ws + F_SRAW;
  float*          pinew = ws + F_PINEW;
  unsigned short* wbuf  = (unsigned short*)(ws + F_WB);
  float*          pool2 = ws + F_POOL2;   // overlays rawp1 (dead after conv2)
  float*          hraw  = ws + F_HRAW;
  float*          muB   = ws + F_MU;

  hipMemsetAsync(sraw, 0, 2560 * sizeof(float), stream);

  k_wprep<<<152, 256, 0, stream>>>(c2w, wbuf);
  k_conv1_fused<<<8192, 512, 0, stream>>>(x, c1w, c1b, g1, rawp1, part1);
  k_bn_fin<<<20, 256, 0, stream>>>(part1, 8192, 20, 8192.f * 576.f, g1, be1, bn1);
  k_conv2_mfma<<<2048, 256, 0, stream>>>(rawp1, wbuf, bn1, c2b, g2, c2p, part2);
  k_bn_fin<<<50, 256, 0, stream>>>(part2, 2048, 50, 8192.f * 64.f, g2, be2, bn2);
  k_bnapply<<<6400, 256, 0, stream>>>(c2p, bn2, pool2);
  k_fc1<<<32, 256, 0, stream>>>(pool2, fw, fb, hraw, part3);
  k_bn_fin<<<10, 256, 0, stream>>>(part3, 32, 10, 8192.f, g3, be3, bn3);
  k_theta_mu<<<8192, 256, 0, stream>>>(hraw, bn3, thw, thb, muB);
  k_S<<<128, 256, 0, stream>>>(muB, y, sraw);
  k_pi<<<1, 256, 0, stream>>>(pi, sraw, pinew);
  k_out<<<320, 256, 0, stream>>>(muB, pinew, out);
}

// Round 5
// 279.630 us; speedup vs baseline: 3.5356x; 1.2898x over previous
//
#include <hip/hip_runtime.h>
#include <hip/hip_bf16.h>
#include <math.h>

typedef __attribute__((ext_vector_type(8))) short short8v;
typedef __attribute__((ext_vector_type(4))) float float4v;

// ---------------- workspace layout (dword offsets) ----------------
static const size_t F_RAWP1 = 0;               // fp32 ch-last pooled raw conv1 [8192][144][24] = 28,311,552
static const size_t F_C2P   = 28311552;        // fp32 pooled raw conv2 [8192][800] = 6,553,600
static const size_t F_PART1 = 34865152;        // 8192*40
static const size_t F_PART2 = 35192832;        // 2048*100
static const size_t F_PART3 = 35397632;        // 256*20
static const size_t F_BN1   = 35402752;        // 40
static const size_t F_BN2   = 35402792;        // 100
static const size_t F_BN3   = 35402892;        // 20
static const size_t F_SRAW  = 35402912;        // 2560
static const size_t F_PINEW = 35405472;        // 2560
static const size_t F_WB2   = 35408032;        // 19456 dwords (76*64*8 bf16)
static const size_t F_WB1   = 35427488;        // 512 dwords (32*32 bf16)
// overlays in rawp1 region (dead after conv2):
static const size_t F_HRAW  = 0;               // 8192*10
static const size_t F_MU    = 81920;           // 8192*256

__device__ __forceinline__ float relu_(float v) { return v > 0.f ? v : 0.f; }

__device__ __forceinline__ unsigned int pack_bf16x2(float a, float b) {
  __hip_bfloat16 ha = __float2bfloat16(a), hb = __float2bfloat16(b);
  unsigned short ua, ub;
  __builtin_memcpy(&ua, &ha, 2); __builtin_memcpy(&ub, &hb, 2);
  return ((unsigned int)ub << 16) | ua;
}

__device__ __forceinline__ float pick_(float a, float b, bool mx) {
  return mx ? fmaxf(a, b) : fminf(a, b);
}

// ---- conv1 weight prep: (20,1,5,5) -> wb1[n(32)][k(32)] bf16 ----
__global__ __launch_bounds__(256) void k_wprep1(
    const float* __restrict__ w, unsigned short* __restrict__ wb1)
{
  const int i = blockIdx.x * 256 + threadIdx.x;   // 1024
  const int n = i >> 5, k = i & 31;
  float v = (n < 20 && k < 25) ? w[n*25 + k] : 0.f;
  __hip_bfloat16 h = __float2bfloat16(v);
  unsigned short u; __builtin_memcpy(&u, &h, 2);
  wb1[i] = u;
}

// ---- conv2 weight prep: OIHW fp32 -> wb2[cc(76)][n(64)][j(8)] bf16 ----
__global__ __launch_bounds__(256) void k_wprep2(
    const float* __restrict__ w, unsigned short* __restrict__ wb)
{
  const int idx = blockIdx.x * 256 + threadIdx.x;    // 38912
  const int cc = idx >> 9;
  const int rem = idx & 511;
  const int n = rem >> 3, j = rem & 7;
  float v = 0.f;
  if (cc < 75 && n < 50) {
    const int khw = cc / 3, icg = cc - khw*3;
    const int ic = icg*8 + j;
    if (ic < 20) {
      const int kh = khw / 5, kw = khw - kh*5;
      v = w[((n*20 + ic)*5 + kh)*5 + kw];
    }
  }
  __hip_bfloat16 h = __float2bfloat16(v);
  unsigned short u; __builtin_memcpy(&u, &h, 2);
  wb[idx] = u;
}

// ---- conv1 as MFMA implicit GEMM (1 img/block), in-lane 2x2 pool ----
// Pixel mapping: tile T (=wave*9+tt), row m in [0,16): q = T*4 + (m>>2),
// (py,px) = (q/12, q%12), oy = 2py + ((m&3)>>1), ox = 2px + (m&1).
// C/D: col=lane&15 (oc), row=(lane>>4)*4+r -> lane(hi,lo) quartet r=0..3 =
// one 2x2 pool window of pixel q=T*4+hi, oc=lo. Pool is fully in-lane.
// Output: fp32 ch-last pooled raw [img][144][24] (ch 20..23 unwritten/unread).
__global__ __launch_bounds__(256) void k_conv1_mfma(
    const float* __restrict__ x, const unsigned short* __restrict__ wb1,
    const float* __restrict__ g1, float* __restrict__ rawp1,
    float* __restrict__ part)
{
  __shared__ alignas(16) float xs[784];
  __shared__ float sred[4][32], qred[4][32];
  const int tid = threadIdx.x, img = blockIdx.x;
  const float* xp = x + (size_t)img * 784;
  for (int i = tid; i < 784; i += 256) xs[i] = xp[i];
  __syncthreads();
  const int wave = tid >> 6, lane = tid & 63, lo = lane & 15, hi = lane >> 4;

  // B fragments: lane holds W[n=lo (+16)][k=hi*8+j]
  const short8v bfr0 = *(const short8v*)(wb1 + (lo*32 + hi*8));
  const short8v bfr1 = *(const short8v*)(wb1 + ((16+lo)*32 + hi*8));

  int koff[8];
  #pragma unroll
  for (int j = 0; j < 8; ++j) {
    const int k = hi*8 + j;
    const int kh = k / 5, kw = k - kh*5;
    koff[j] = (k < 25) ? (kh*28 + kw) : -1;
  }

  float4v acc[9][2];
  #pragma unroll
  for (int t = 0; t < 9; ++t) {
    acc[t][0] = (float4v){0.f,0.f,0.f,0.f};
    acc[t][1] = (float4v){0.f,0.f,0.f,0.f};
  }

  #pragma unroll
  for (int tt = 0; tt < 9; ++tt) {
    const int T = wave*9 + tt;
    const int q = T*4 + (lo >> 2);
    const int py = q / 12, px = q - py*12;
    const int oy = 2*py + ((lo >> 1) & 1), ox = 2*px + (lo & 1);
    const float* xb = xs + oy*28 + ox;
    union { unsigned int u[4]; short8v v; } cu;
    #pragma unroll
    for (int jj = 0; jj < 4; ++jj) {
      const float a = (koff[2*jj]   >= 0) ? xb[koff[2*jj]]   : 0.f;
      const float b = (koff[2*jj+1] >= 0) ? xb[koff[2*jj+1]] : 0.f;
      cu.u[jj] = pack_bf16x2(a, b);
    }
    acc[tt][0] = __builtin_amdgcn_mfma_f32_16x16x32_bf16(cu.v, bfr0, acc[tt][0], 0, 0, 0);
    acc[tt][1] = __builtin_amdgcn_mfma_f32_16x16x32_bf16(cu.v, bfr1, acc[tt][1], 0, 0, 0);
  }

  // epilogue: stats (pre-pool) + in-lane sign-aware 2x2 pool + fp32 store
  const bool gp0 = (g1[lo] >= 0.f);
  const bool gp1 = (lo < 4) ? (g1[16+lo] >= 0.f) : true;
  float sv0 = 0.f, qv0 = 0.f, sv1 = 0.f, qv1 = 0.f;
  float* dst = rawp1 + (size_t)img * 3456;
  #pragma unroll
  for (int tt = 0; tt < 9; ++tt) {
    const int T = wave*9 + tt;
    const int q = T*4 + hi;
    const float4v v0 = acc[tt][0];
    const float4v v1 = acc[tt][1];
    #pragma unroll
    for (int r = 0; r < 4; ++r) { sv0 += v0[r]; qv0 += v0[r]*v0[r]; }
    #pragma unroll
    for (int r = 0; r < 4; ++r) { sv1 += v1[r]; qv1 += v1[r]*v1[r]; }
    const float p0 = pick_(pick_(v0[0], v0[1], gp0), pick_(v0[2], v0[3], gp0), gp0);
    const float p1 = pick_(pick_(v1[0], v1[1], gp1), pick_(v1[2], v1[3], gp1), gp1);
    const float o0 = __shfl_down(p0, 1);
    const float o1 = __shfl_down(p1, 1);
    if ((lo & 1) == 0) {
      float2 w0; w0.x = p0; w0.y = o0;
      *(float2*)(dst + q*24 + lo) = w0;              // oc pair (lo, lo+1)
      if (lo < 4) {
        float2 w1; w1.x = p1; w1.y = o1;
        *(float2*)(dst + q*24 + 16 + lo) = w1;       // oc pair (16+lo, 17+lo)
      }
    }
  }
  sv0 += __shfl_down(sv0, 32); qv0 += __shfl_down(qv0, 32);
  sv0 += __shfl_down(sv0, 16); qv0 += __shfl_down(qv0, 16);
  sv1 += __shfl_down(sv1, 32); qv1 += __shfl_down(qv1, 32);
  sv1 += __shfl_down(sv1, 16); qv1 += __shfl_down(qv1, 16);
  if (hi == 0) {
    sred[wave][lo] = sv0; sred[wave][16+lo] = sv1;
    qred[wave][lo] = qv0; qred[wave][16+lo] = qv1;
  }
  __syncthreads();
  if (tid < 20) {
    float s = 0.f, q = 0.f;
    #pragma unroll
    for (int w2 = 0; w2 < 4; ++w2) { s += sred[w2][tid]; q += qred[w2][tid]; }
    part[(size_t)img*40 + tid]      = s;
    part[(size_t)img*40 + 20 + tid] = q;
  }
}

// ---- conv2 implicit-GEMM MFMA (R3-verified); staging: BN1+ReLU+bf16 pack;
//      epilogue: BN2 partial stats + in-register sign-aware 2x2 pool ----
__global__ __launch_bounds__(256) void k_conv2_mfma(
    const float* __restrict__ rawp1, const unsigned short* __restrict__ wb,
    const float* __restrict__ bn1, const float* __restrict__ g2,
    float* __restrict__ c2p, float* __restrict__ part)
{
  __shared__ alignas(16) unsigned int in4[6912];     // 4 imgs, bf16 ch-last [144][12dw]
  __shared__ float sred[4][64], qred[4][64];
  __shared__ float sc1[20], sh1[20];
  const int tid = threadIdx.x, blk = blockIdx.x;
  if (tid < 20) { sc1[tid] = bn1[tid]; sh1[tid] = bn1[20 + tid]; }
  __syncthreads();
  const float* src = rawp1 + (size_t)blk * 13824;
  for (int d = tid; d < 6912; d += 256) {
    const int il = d / 1728, r = d - il*1728;
    const int pix = r / 12, chp = r - pix*12;
    unsigned int pv = 0u;
    if (chp < 10) {
      const float2 v = *(const float2*)(src + (size_t)il*3456 + pix*24 + 2*chp);
      const float a = relu_(v.x * sc1[2*chp]   + sh1[2*chp]);
      const float b = relu_(v.y * sc1[2*chp+1] + sh1[2*chp+1]);
      pv = pack_bf16x2(a, b);
    }
    in4[d] = pv;
  }
  __syncthreads();

  const int wave = tid >> 6, lane = tid & 63;
  const int lo = lane & 15, hi = lane >> 4;
  const char* ibase = (const char*)in4 + wave * 6912;

  int pixb[4];
  #pragma unroll
  for (int a = 0; a < 4; ++a) { const int m = a*16 + lo; pixb[a] = (m >> 3) * 12 + (m & 7); }
  bool gpos[4];
  #pragma unroll
  for (int nf = 0; nf < 4; ++nf) {
    const int n = nf*16 + lo;
    gpos[nf] = (n < 50) ? (g2[n] >= 0.f) : true;
  }

  float4v acc[4][4];
  #pragma unroll
  for (int a = 0; a < 4; ++a)
    #pragma unroll
    for (int nf = 0; nf < 4; ++nf) acc[a][nf] = (float4v){0.f, 0.f, 0.f, 0.f};

  for (int s = 0; s < 19; ++s) {
    const int cc = s*4 + hi;                 // 0..75 (75 = zero weight chunk)
    const int cca = cc > 74 ? 74 : cc;
    const int khw = cca / 3, icg = cca - khw*3;
    const int kh = khw / 5, kw = khw - kh*5;
    const int khoff = kh*12 + kw;
    short8v av[4];
    #pragma unroll
    for (int am = 0; am < 4; ++am)
      av[am] = *(const short8v*)(ibase + (size_t)(pixb[am] + khoff)*48 + icg*16);
    short8v bv[4];
    const unsigned short* wrow = wb + (size_t)cc*512 + lo*8;
    #pragma unroll
    for (int nf = 0; nf < 4; ++nf)
      bv[nf] = *(const short8v*)(wrow + nf*128);
    #pragma unroll
    for (int am = 0; am < 4; ++am)
      #pragma unroll
      for (int nf = 0; nf < 4; ++nf)
        acc[am][nf] = __builtin_amdgcn_mfma_f32_16x16x32_bf16(av[am], bv[nf], acc[am][nf], 0, 0, 0);
  }

  const int img = blk*4 + wave;
  #pragma unroll
  for (int nf = 0; nf < 4; ++nf) {
    const int n = nf*16 + lo;
    float sv = 0.f, qv = 0.f;
    #pragma unroll
    for (int am = 0; am < 4; ++am) {
      float4v v = acc[am][nf];
      #pragma unroll
      for (int r = 0; r < 4; ++r) { sv += v[r]; qv += v[r]*v[r]; }
      float h0 = gpos[nf] ? fmaxf(v[0], v[1]) : fminf(v[0], v[1]);
      float h1 = gpos[nf] ? fmaxf(v[2], v[3]) : fminf(v[2], v[3]);
      const float o0 = __shfl_xor(h0, 32);
      const float o1 = __shfl_xor(h1, 32);
      h0 = gpos[nf] ? fmaxf(h0, o0) : fminf(h0, o0);
      h1 = gpos[nf] ? fmaxf(h1, o1) : fminf(h1, o1);
      if (hi < 2 && n < 50) {
        float2 o; o.x = h0; o.y = h1;
        *(float2*)(c2p + (size_t)img*800 + n*16 + am*4 + hi*2) = o;
      }
    }
    sv += __shfl_down(sv, 32); qv += __shfl_down(qv, 32);
    sv += __shfl_down(sv, 16); qv += __shfl_down(qv, 16);
    if (hi == 0) { sred[wave][nf*16 + lo] = sv; qred[wave][nf*16 + lo] = qv; }
  }
  __syncthreads();
  if (tid < 100) {
    const int ch = tid < 50 ? tid : tid - 50;
    float t = 0.f;
    if (tid < 50) {
      #pragma unroll
      for (int w2 = 0; w2 < 4; ++w2) t += sred[w2][ch];
      part[(size_t)blk*100 + ch] = t;
    } else {
      #pragma unroll
      for (int w2 = 0; w2 < 4; ++w2) t += qred[w2][ch];
      part[(size_t)blk*100 + 50 + ch] = t;
    }
  }
}

// ---- BN finalize: reduce per-block partials (double), emit scale/shift ----
__global__ __launch_bounds__(256) void k_bn_fin(
    const float* __restrict__ part, int nblk, int nch, float N,
    const float* __restrict__ g, const float* __restrict__ b,
    float* __restrict__ out)
{
  __shared__ double rd[4][2];
  const int tid = threadIdx.x, ch = blockIdx.x;
  const int lane = tid & 63, wid = tid >> 6;
  double s = 0.0, q = 0.0;
  for (int i = tid; i < nblk; i += 256) {
    s += (double)part[(size_t)i*2*nch + ch];
    q += (double)part[(size_t)i*2*nch + nch + ch];
  }
  #pragma unroll
  for (int off = 32; off > 0; off >>= 1) { s += __shfl_down(s, off); q += __shfl_down(q, off); }
  if (lane == 0) { rd[wid][0] = s; rd[wid][1] = q; }
  __syncthreads();
  if (tid == 0) {
    double S = rd[0][0] + rd[1][0] + rd[2][0] + rd[3][0];
    double Q = rd[0][1] + rd[1][1] + rd[2][1] + rd[3][1];
    double mean = S / (double)N;
    double var  = Q / (double)N - mean * mean;
    if (var < 0.0) var = 0.0;
    float scv = (float)((double)g[ch] / sqrt(var + 1e-5));
    out[ch]       = scv;
    out[nch + ch] = b[ch] - (float)mean * scv;
  }
}

// ---- fc1 fused BN2+ReLU: 32 samples/block, 8-lane K-split ----
__global__ __launch_bounds__(256) void k_fc1(
    const float* __restrict__ c2p, const float* __restrict__ bn2,
    const float* __restrict__ fw, float* __restrict__ h_raw,
    float* __restrict__ part)
{
  __shared__ alignas(16) float wl[8000];
  __shared__ float s2[50], h2[50];
  __shared__ float red[4][20];
  const int tid = threadIdx.x;
  for (int i = tid; i < 2000; i += 256)
    ((float4*)wl)[i] = ((const float4*)fw)[i];
  if (tid < 50) { s2[tid] = bn2[tid]; h2[tid] = bn2[50 + tid]; }
  __syncthreads();
  const int s = tid >> 3, kc = tid & 7;
  const int sample = blockIdx.x * 32 + s;
  const float* xr = c2p + (size_t)sample * 800 + kc * 100;
  float acc[10];
  #pragma unroll
  for (int f = 0; f < 10; ++f) acc[f] = 0.f;
  #pragma unroll 5
  for (int c = 0; c < 25; ++c) {
    const int k = kc*100 + c*4;
    float4 v = *(const float4*)(xr + c*4);
    const int oc = k >> 4;
    const float sc = s2[oc], sh = h2[oc];
    v.x = relu_(v.x*sc + sh); v.y = relu_(v.y*sc + sh);
    v.z = relu_(v.z*sc + sh); v.w = relu_(v.w*sc + sh);
    #pragma unroll
    for (int f = 0; f < 10; ++f) {
      const float4 wv = *(const float4*)(wl + f*800 + k);
      acc[f] += v.x*wv.x + v.y*wv.y + v.z*wv.z + v.w*wv.w;
    }
  }
  const int lane = tid & 63, wid = tid >> 6;
  #pragma unroll
  for (int f = 0; f < 10; ++f) {
    acc[f] += __shfl_down(acc[f], 4);
    acc[f] += __shfl_down(acc[f], 2);
    acc[f] += __shfl_down(acc[f], 1);
    float a2 = (kc == 0) ? acc[f] : 0.f;
    float q2 = (kc == 0) ? acc[f]*acc[f] : 0.f;
    if (kc == 0) h_raw[(size_t)sample*10 + f] = acc[f];
    a2 += __shfl_down(a2, 32); q2 += __shfl_down(q2, 32);
    a2 += __shfl_down(a2, 16); q2 += __shfl_down(q2, 16);
    a2 += __shfl_down(a2, 8);  q2 += __shfl_down(q2, 8);
    if (lane == 0) { red[wid][f] = a2; red[wid][10+f] = q2; }
  }
  __syncthreads();
  if (tid < 20) {
    float t = 0.f;
    #pragma unroll
    for (int w2 = 0; w2 < 4; ++w2) t += red[w2][tid];
    part[(size_t)blockIdx.x*20 + tid] = t;
  }
}

// ---- BN3+ReLU, theta logits -> sigmoid, tree walk -> mu (32 samples/blk) ----
__global__ __launch_bounds__(256) void k_theta_mu(
    const float* __restrict__ h_raw, const float* __restrict__ bn3,
    const float* __restrict__ tw, const float* __restrict__ tb,
    float* __restrict__ mu)
{
  __shared__ float twt[10][256];
  __shared__ float tbl[256];
  __shared__ float hl[32][10];
  __shared__ float pl[32][256];
  const int tid = threadIdx.x, blk = blockIdx.x;
  for (int i = tid; i < 2550; i += 256) {
    const int node = i / 10, f = i - node*10;
    twt[f][node] = tw[i];
  }
  if (tid < 10) twt[tid][255] = 0.f;
  tbl[tid] = (tid < 255) ? tb[tid] : 0.f;
  for (int i = tid; i < 320; i += 256) {
    const int ss = i / 10, f = i - ss*10;
    hl[ss][f] = relu_(h_raw[(size_t)blk*320 + i] * bn3[f] + bn3[10 + f]);
  }
  __syncthreads();
  const int node = tid;
  for (int i2 = 0; i2 < 32; ++i2) {
    float h[10];
    #pragma unroll
    for (int f = 0; f < 10; ++f) h[f] = hl[i2][f];
    float d = tbl[node];
    #pragma unroll
    for (int f = 0; f < 10; ++f) d += h[f] * twt[f][node];
    pl[i2][node] = (node < 255) ? 1.f / (1.f + __expf(-d)) : 0.f;
  }
  __syncthreads();
  for (int i2 = 0; i2 < 32; ++i2) {
    float m = 1.f; int idx = 0;
    #pragma unroll
    for (int k = 0; k < 8; ++k) {
      const int dir = (tid >> (7 - k)) & 1;
      const float pv = pl[i2][idx];
      m *= dir ? pv : (1.f - pv);
      idx += dir ? (1 << (7 - k)) : 1;
    }
    mu[(size_t)(blk*32 + i2)*256 + tid] = m;
  }
}

// ---- S_raw[l,c] = sum over samples of class c of mu[b,l] ----
__global__ __launch_bounds__(256) void k_S(
    const float* __restrict__ mu, const int* __restrict__ y,
    float* __restrict__ S)
{
  const int tid = threadIdx.x;
  const int b0 = blockIdx.x * 64;
  float acc[10];
  #pragma unroll
  for (int c = 0; c < 10; ++c) acc[c] = 0.f;
  for (int s = 0; s < 64; ++s) {
    const int b = b0 + s;
    const float m = mu[(size_t)b*256 + tid];
    const int c = y[b];
    #pragma unroll
    for (int cc = 0; cc < 10; ++cc) acc[cc] += (c == cc) ? m : 0.f;
  }
  #pragma unroll
  for (int cc = 0; cc < 10; ++cc) atomicAdd(&S[tid*10 + cc], acc[cc]);
}

// ---- pi EM update (tiny, one block; thread = leaf) ----
__global__ __launch_bounds__(256) void k_pi(
    const float* __restrict__ pi, const float* __restrict__ S,
    float* __restrict__ pi_new)
{
  __shared__ float pin[2560];
  __shared__ float Pp[10];
  const int t = threadIdx.x;
  float row[10]; float rs = 0.f;
  #pragma unroll
  for (int c = 0; c < 10; ++c) { row[c] = pi[t*10 + c]; rs += row[c]; }
  #pragma unroll
  for (int c = 0; c < 10; ++c) { row[c] /= rs; pin[t*10 + c] = row[c]; }
  __syncthreads();
  if (t < 10) {
    float s = 0.f;
    for (int l = 0; l < 256; ++l) s += pin[l*10 + t];
    Pp[t] = s / 256.f;
  }
  __syncthreads();
  float hs = 0.f; float ph[10];
  #pragma unroll
  for (int c = 0; c < 10; ++c) {
    const float Sv = S[t*10 + c] / Pp[c];
    ph[c] = row[c] * Sv;
    hs += ph[c];
  }
  #pragma unroll
  for (int c = 0; c < 10; ++c) pi_new[t*10 + c] = ph[c] / hs;
}

// ---- out = log(mu @ pi_new) ----
__global__ __launch_bounds__(256) void k_out(
    const float* __restrict__ mu, const float* __restrict__ pn,
    float* __restrict__ out)
{
  __shared__ float pl[2560];
  const int tid = threadIdx.x;
  for (int i = tid; i < 2560; i += 256) pl[i] = pn[i];
  __syncthreads();
  const int gid = blockIdx.x * 256 + tid;
  const int b = gid / 10, c = gid % 10;
  const float* mr = mu + (size_t)b * 256;
  float acc = 0.f;
  for (int l = 0; l < 256; ++l) acc += mr[l] * pl[l*10 + c];
  out[gid] = logf(acc);
}

extern "C" void kernel_launch(void* const* d_in, const int* in_sizes, int n_in,
                              void* d_out, int out_size, void* d_ws, size_t ws_size,
                              hipStream_t stream)
{
  const float* x   = (const float*)d_in[0];
  const int*   y   = (const int*)  d_in[1];
  const float* c1w = (const float*)d_in[2];
  const float* c2w = (const float*)d_in[4];
  const float* g1  = (const float*)d_in[6];
  const float* be1 = (const float*)d_in[7];
  const float* g2  = (const float*)d_in[8];
  const float* be2 = (const float*)d_in[9];
  const float* fw  = (const float*)d_in[10];
  const float* g3  = (const float*)d_in[12];
  const float* be3 = (const float*)d_in[13];
  const float* thw = (const float*)d_in[14];
  const float* thb = (const float*)d_in[15];
  const float* pi  = (const float*)d_in[16];
  float* ws  = (float*)d_ws;
  float* out = (float*)d_out;

  float*          rawp1 = ws + F_RAWP1;
  float*          c2p   = ws + F_C2P;
  float*          part1 = ws + F_PART1;
  float*          part2 = ws + F_PART2;
  float*          part3 = ws + F_PART3;
  float*          bn1   = ws + F_BN1;
  float*          bn2   = ws + F_BN2;
  float*          bn3   = ws + F_BN3;
  float*          sraw  = ws + F_SRAW;
  float*          pinew = ws + F_PINEW;
  unsigned short* wb2   = (unsigned short*)(ws + F_WB2);
  unsigned short* wb1   = (unsigned short*)(ws + F_WB1);
  float*          hraw  = ws + F_HRAW;   // overlays rawp1 (dead after conv2)
  float*          muB   = ws + F_MU;

  hipMemsetAsync(sraw, 0, 2560 * sizeof(float), stream);

  k_wprep1<<<4, 256, 0, stream>>>(c1w, wb1);
  k_wprep2<<<152, 256, 0, stream>>>(c2w, wb2);
  k_conv1_mfma<<<8192, 256, 0, stream>>>(x, wb1, g1, rawp1, part1);
  k_bn_fin<<<20, 256, 0, stream>>>(part1, 8192, 20, 8192.f * 576.f, g1, be1, bn1);
  k_conv2_mfma<<<2048, 256, 0, stream>>>(rawp1, wb2, bn1, g2, c2p, part2);
  k_bn_fin<<<50, 256, 0, stream>>>(part2, 2048, 50, 8192.f * 64.f, g2, be2, bn2);
  k_fc1<<<256, 256, 0, stream>>>(c2p, bn2, fw, hraw, part3);
  k_bn_fin<<<10, 256, 0, stream>>>(part3, 256, 10, 8192.f, g3, be3, bn3);
  k_theta_mu<<<256, 256, 0, stream>>>(hraw, bn3, thw, thb, muB);
  k_S<<<128, 256, 0, stream>>>(muB, y, sraw);
  k_pi<<<1, 256, 0, stream>>>(pi, sraw, pinew);
  k_out<<<320, 256, 0, stream>>>(muB, pinew, out);
}

// Round 6
// 243.372 us; speedup vs baseline: 4.0624x; 1.1490x over previous
//
#include <hip/hip_runtime.h>
#include <hip/hip_bf16.h>
#include <math.h>

typedef __attribute__((ext_vector_type(8))) short short8v;
typedef __attribute__((ext_vector_type(4))) float float4v;

// ---------------- workspace layout (dword offsets) ----------------
static const size_t F_RAWP1B = 0;              // bf16 ch-last pooled raw conv1 [8192][144][12dw] = 14,155,776
static const size_t F_C2P    = 14155776;       // fp32 pooled raw conv2 [8192][800] = 6,553,600
static const size_t F_PART1  = 20709376;       // 8192*40
static const size_t F_PART2  = 21037056;       // 2048*100
static const size_t F_PART3  = 21241856;       // 256*20
static const size_t F_BN1    = 21246976;       // 40
static const size_t F_BN2    = 21247016;       // 100
static const size_t F_BN3    = 21247116;       // 20
static const size_t F_SRAW   = 21247136;       // 2560
static const size_t F_PINEW  = 21249696;       // 2560
static const size_t F_WB2    = 21252256;       // 19456 (76*64*8 bf16)
static const size_t F_WB1    = 21271712;       // 512   (32*32 bf16)
// overlays in rawp1b region (dead after conv2):
static const size_t F_HRAW   = 0;              // 8192*10
static const size_t F_MU     = 81920;          // 8192*256

__device__ __forceinline__ float relu_(float v) { return v > 0.f ? v : 0.f; }

__device__ __forceinline__ unsigned int pack_bf16x2(float a, float b) {
  __hip_bfloat16 ha = __float2bfloat16(a), hb = __float2bfloat16(b);
  unsigned short ua, ub;
  __builtin_memcpy(&ua, &ha, 2); __builtin_memcpy(&ub, &hb, 2);
  return ((unsigned int)ub << 16) | ua;
}

__device__ __forceinline__ float pick_(float a, float b, bool mx) {
  return mx ? fmaxf(a, b) : fminf(a, b);
}

// ---- conv1 weight prep: (20,1,5,5) -> wb1[n(32)][k(32)] bf16, k = kh*6+kw ----
__global__ __launch_bounds__(256) void k_wprep1(
    const float* __restrict__ w, unsigned short* __restrict__ wb1)
{
  const int i = blockIdx.x * 256 + threadIdx.x;   // 1024
  const int n = i >> 5, k = i & 31;
  const int kh = k / 6, kw = k - kh*6;
  float v = (n < 20 && kh < 5 && kw < 5) ? w[n*25 + kh*5 + kw] : 0.f;
  __hip_bfloat16 h = __float2bfloat16(v);
  unsigned short u; __builtin_memcpy(&u, &h, 2);
  wb1[i] = u;
}

// ---- conv2 weight prep: OIHW fp32 -> wb2[cc(76)][n(64)][j(8)] bf16 ----
__global__ __launch_bounds__(256) void k_wprep2(
    const float* __restrict__ w, unsigned short* __restrict__ wb)
{
  const int idx = blockIdx.x * 256 + threadIdx.x;    // 38912
  const int cc = idx >> 9;
  const int rem = idx & 511;
  const int n = rem >> 3, j = rem & 7;
  float v = 0.f;
  if (cc < 75 && n < 50) {
    const int khw = cc / 3, icg = cc - khw*3;
    const int ic = icg*8 + j;
    if (ic < 20) {
      const int kh = khw / 5, kw = khw - kh*5;
      v = w[((n*20 + ic)*5 + kh)*5 + kw];
    }
  }
  __hip_bfloat16 h = __float2bfloat16(v);
  unsigned short u; __builtin_memcpy(&u, &h, 2);
  wb[idx] = u;
}

// ---- conv1 MFMA implicit GEMM, packed-pair dual-copy LDS gather ----
// k-map: k = kh*6+kw. A pair (2j,2j+1) = x[oy+kh][ox+kw], x[oy+kh][ox+kw+1]
// = one aligned dword in parity-copy (ox&1) of the packed image.
// Pixel mapping (verified R5): q = T*4+(lo>>2), oy=2py+((lo>>1)&1), ox=2px+(lo&1);
// C quartet of lane (hi,lo) = 2x2 window of pixel q=T*4+hi, oc=lo -> in-lane pool.
// Output: bf16 packed ch-last pooled raw [img][144][12dw] (48 B/pixel).
__global__ __launch_bounds__(256) void k_conv1_mfma(
    const float* __restrict__ x, const unsigned short* __restrict__ wb1,
    const float* __restrict__ g1, unsigned int* __restrict__ rawp1b,
    float* __restrict__ part)
{
  __shared__ alignas(16) unsigned short xpk[1568];   // [2 copies][28 rows][28 ushort]
  __shared__ float sred[4][32], qred[4][32];
  const int tid = threadIdx.x, img = blockIdx.x;
  const float* xp = x + (size_t)img * 784;
  for (int i = tid; i < 784; i += 256) {
    const int r = i / 28, c = i - r*28;
    __hip_bfloat16 h = __float2bfloat16(xp[i]);
    unsigned short u; __builtin_memcpy(&u, &h, 2);
    xpk[r*28 + c] = u;                         // copy0: pair cols (2d, 2d+1)
    if (c >= 1) xpk[784 + r*28 + (c-1)] = u;   // copy1: pair cols (1+2d, 2+2d)
    else        xpk[784 + r*28 + 27]  = 0;     // copy1 col-28 slot = 0
  }
  __syncthreads();
  const int wave = tid >> 6, lane = tid & 63, lo = lane & 15, hi = lane >> 4;

  const short8v bfr0 = *(const short8v*)(wb1 + (lo*32 + hi*8));
  const short8v bfr1 = *(const short8v*)(wb1 + ((16+lo)*32 + hi*8));

  // per-hi dword offsets (kh*14 + kw/2) for jj=0..3, byte-encoded
  const unsigned enc = (hi==0) ? 0x0E020100u
                     : (hi==1) ? 0x1D1C100Fu
                     : (hi==2) ? 0x2C2B2A1Eu
                     :           0x003A3938u;   // hi=3: jj3 = zero-weight dummy
  const int off0 = enc & 255, off1 = (enc>>8)&255, off2 = (enc>>16)&255, off3 = enc>>24;
  const unsigned int* xpd = (const unsigned int*)xpk;   // 784 dwords
  const int pb   = (lo & 1) * 392;
  const int oyp  = (lo >> 1) & 1, qoff = lo >> 2;

  float4v acc[9][2];
  #pragma unroll
  for (int t = 0; t < 9; ++t) {
    acc[t][0] = (float4v){0.f,0.f,0.f,0.f};
    acc[t][1] = (float4v){0.f,0.f,0.f,0.f};
  }

  #pragma unroll
  for (int tt = 0; tt < 9; ++tt) {
    const int qq  = tt*4 + qoff;          // 0..35 within this wave's strip
    const int pyl = qq / 12;
    const int pxl = qq - pyl*12;
    const int base = pb + (6*wave + 2*pyl + oyp)*14 + pxl;
    union { unsigned int u[4]; short8v v; } cu;
    cu.u[0] = xpd[base + off0];
    cu.u[1] = xpd[base + off1];
    cu.u[2] = xpd[base + off2];
    cu.u[3] = xpd[base + off3];
    acc[tt][0] = __builtin_amdgcn_mfma_f32_16x16x32_bf16(cu.v, bfr0, acc[tt][0], 0, 0, 0);
    acc[tt][1] = __builtin_amdgcn_mfma_f32_16x16x32_bf16(cu.v, bfr1, acc[tt][1], 0, 0, 0);
  }

  // epilogue: stats (pre-pool) + in-lane sign-aware 2x2 pool + bf16 pack store
  const bool gp0 = (g1[lo] >= 0.f);
  const bool gp1 = (lo < 4) ? (g1[16+lo] >= 0.f) : true;
  float sv0 = 0.f, qv0 = 0.f, sv1 = 0.f, qv1 = 0.f;
  unsigned int* dst = rawp1b + (size_t)img * 1728;
  #pragma unroll
  for (int tt = 0; tt < 9; ++tt) {
    const int T = wave*9 + tt;
    const int q = T*4 + hi;
    const float4v v0 = acc[tt][0];
    const float4v v1 = acc[tt][1];
    #pragma unroll
    for (int r = 0; r < 4; ++r) { sv0 += v0[r]; qv0 += v0[r]*v0[r]; }
    #pragma unroll
    for (int r = 0; r < 4; ++r) { sv1 += v1[r]; qv1 += v1[r]*v1[r]; }
    const float p0 = pick_(pick_(v0[0], v0[1], gp0), pick_(v0[2], v0[3], gp0), gp0);
    const float p1 = pick_(pick_(v1[0], v1[1], gp1), pick_(v1[2], v1[3], gp1), gp1);
    const float o0 = __shfl_down(p0, 1);
    const float o1 = __shfl_down(p1, 1);
    if ((lo & 1) == 0) {
      dst[q*12 + (lo >> 1)] = pack_bf16x2(p0, o0);          // oc pair (lo, lo+1)
      if (lo < 8)
        dst[q*12 + 8 + (lo >> 1)] = pack_bf16x2(p1, o1);    // oc 16.. (pads=0)
    }
  }
  sv0 += __shfl_down(sv0, 32); qv0 += __shfl_down(qv0, 32);
  sv0 += __shfl_down(sv0, 16); qv0 += __shfl_down(qv0, 16);
  sv1 += __shfl_down(sv1, 32); qv1 += __shfl_down(qv1, 32);
  sv1 += __shfl_down(sv1, 16); qv1 += __shfl_down(qv1, 16);
  if (hi == 0) {
    sred[wave][lo] = sv0; sred[wave][16+lo] = sv1;
    qred[wave][lo] = qv0; qred[wave][16+lo] = qv1;
  }
  __syncthreads();
  if (tid < 20) {
    float s = 0.f, q = 0.f;
    #pragma unroll
    for (int w2 = 0; w2 < 4; ++w2) { s += sred[w2][tid]; q += qred[w2][tid]; }
    part[(size_t)img*40 + tid]      = s;
    part[(size_t)img*40 + 20 + tid] = q;
  }
}

// ---- conv2 implicit-GEMM MFMA; staging: unpack bf16 pair + BN1+ReLU + repack
//      (R4-audited staging; R3/R5-verified *48B pixel-stride A-read);
//      epilogue: BN2 partial stats + in-register sign-aware 2x2 pool ----
__global__ __launch_bounds__(256) void k_conv2_mfma(
    const unsigned int* __restrict__ rawp1b, const unsigned short* __restrict__ wb,
    const float* __restrict__ bn1, const float* __restrict__ g2,
    float* __restrict__ c2p, float* __restrict__ part)
{
  __shared__ alignas(16) unsigned int in4[6912];     // 4 imgs, bf16 ch-last [144][12dw]
  __shared__ float sred[4][64], qred[4][64];
  __shared__ float sc1[20], sh1[20];
  const int tid = threadIdx.x, blk = blockIdx.x;
  if (tid < 20) { sc1[tid] = bn1[tid]; sh1[tid] = bn1[20 + tid]; }
  __syncthreads();
  const unsigned int* src = rawp1b + (size_t)blk * 6912;
  for (int d = tid; d < 6912; d += 256) {
    const unsigned int u = src[d];
    const int chp = d % 12;
    unsigned int pv = 0u;
    if (chp < 10) {
      const float a = __uint_as_float(u << 16);
      const float b = __uint_as_float(u & 0xffff0000u);
      const float ra = relu_(a * sc1[2*chp]   + sh1[2*chp]);
      const float rb = relu_(b * sc1[2*chp+1] + sh1[2*chp+1]);
      pv = pack_bf16x2(ra, rb);
    }
    in4[d] = pv;
  }
  __syncthreads();

  const int wave = tid >> 6, lane = tid & 63;
  const int lo = lane & 15, hi = lane >> 4;
  const char* ibase = (const char*)in4 + wave * 6912;

  int pixb[4];
  #pragma unroll
  for (int a = 0; a < 4; ++a) { const int m = a*16 + lo; pixb[a] = (m >> 3) * 12 + (m & 7); }
  bool gpos[4];
  #pragma unroll
  for (int nf = 0; nf < 4; ++nf) {
    const int n = nf*16 + lo;
    gpos[nf] = (n < 50) ? (g2[n] >= 0.f) : true;
  }

  float4v acc[4][4];
  #pragma unroll
  for (int a = 0; a < 4; ++a)
    #pragma unroll
    for (int nf = 0; nf < 4; ++nf) acc[a][nf] = (float4v){0.f, 0.f, 0.f, 0.f};

  for (int s = 0; s < 19; ++s) {
    const int cc = s*4 + hi;                 // 0..75 (75 = zero weight chunk)
    const int cca = cc > 74 ? 74 : cc;
    const int khw = cca / 3, icg = cca - khw*3;
    const int kh = khw / 5, kw = khw - kh*5;
    const int khoff = kh*12 + kw;
    short8v av[4];
    #pragma unroll
    for (int am = 0; am < 4; ++am)
      av[am] = *(const short8v*)(ibase + (size_t)(pixb[am] + khoff)*48 + icg*16);
    short8v bv[4];
    const unsigned short* wrow = wb + (size_t)cc*512 + lo*8;
    #pragma unroll
    for (int nf = 0; nf < 4; ++nf)
      bv[nf] = *(const short8v*)(wrow + nf*128);
    #pragma unroll
    for (int am = 0; am < 4; ++am)
      #pragma unroll
      for (int nf = 0; nf < 4; ++nf)
        acc[am][nf] = __builtin_amdgcn_mfma_f32_16x16x32_bf16(av[am], bv[nf], acc[am][nf], 0, 0, 0);
  }

  const int img = blk*4 + wave;
  #pragma unroll
  for (int nf = 0; nf < 4; ++nf) {
    const int n = nf*16 + lo;
    float sv = 0.f, qv = 0.f;
    #pragma unroll
    for (int am = 0; am < 4; ++am) {
      float4v v = acc[am][nf];
      #pragma unroll
      for (int r = 0; r < 4; ++r) { sv += v[r]; qv += v[r]*v[r]; }
      float h0 = gpos[nf] ? fmaxf(v[0], v[1]) : fminf(v[0], v[1]);
      float h1 = gpos[nf] ? fmaxf(v[2], v[3]) : fminf(v[2], v[3]);
      const float o0 = __shfl_xor(h0, 32);
      const float o1 = __shfl_xor(h1, 32);
      h0 = gpos[nf] ? fmaxf(h0, o0) : fminf(h0, o0);
      h1 = gpos[nf] ? fmaxf(h1, o1) : fminf(h1, o1);
      if (hi < 2 && n < 50) {
        float2 o; o.x = h0; o.y = h1;
        *(float2*)(c2p + (size_t)img*800 + n*16 + am*4 + hi*2) = o;
      }
    }
    sv += __shfl_down(sv, 32); qv += __shfl_down(qv, 32);
    sv += __shfl_down(sv, 16); qv += __shfl_down(qv, 16);
    if (hi == 0) { sred[wave][nf*16 + lo] = sv; qred[wave][nf*16 + lo] = qv; }
  }
  __syncthreads();
  if (tid < 100) {
    const int ch = tid < 50 ? tid : tid - 50;
    float t = 0.f;
    if (tid < 50) {
      #pragma unroll
      for (int w2 = 0; w2 < 4; ++w2) t += sred[w2][ch];
      part[(size_t)blk*100 + ch] = t;
    } else {
      #pragma unroll
      for (int w2 = 0; w2 < 4; ++w2) t += qred[w2][ch];
      part[(size_t)blk*100 + 50 + ch] = t;
    }
  }
}

// ---- BN finalize: reduce per-block partials (double), emit scale/shift ----
__global__ __launch_bounds__(256) void k_bn_fin(
    const float* __restrict__ part, int nblk, int nch, float N,
    const float* __restrict__ g, const float* __restrict__ b,
    float* __restrict__ out)
{
  __shared__ double rd[4][2];
  const int tid = threadIdx.x, ch = blockIdx.x;
  const int lane = tid & 63, wid = tid >> 6;
  double s = 0.0, q = 0.0;
  for (int i = tid; i < nblk; i += 256) {
    s += (double)part[(size_t)i*2*nch + ch];
    q += (double)part[(size_t)i*2*nch + nch + ch];
  }
  #pragma unroll
  for (int off = 32; off > 0; off >>= 1) { s += __shfl_down(s, off); q += __shfl_down(q, off); }
  if (lane == 0) { rd[wid][0] = s; rd[wid][1] = q; }
  __syncthreads();
  if (tid == 0) {
    double S = rd[0][0] + rd[1][0] + rd[2][0] + rd[3][0];
    double Q = rd[0][1] + rd[1][1] + rd[2][1] + rd[3][1];
    double mean = S / (double)N;
    double var  = Q / (double)N - mean * mean;
    if (var < 0.0) var = 0.0;
    float scv = (float)((double)g[ch] / sqrt(var + 1e-5));
    out[ch]       = scv;
    out[nch + ch] = b[ch] - (float)mean * scv;
  }
}

// ---- fc1 fused BN2+ReLU: 32 samples/block, 8-lane K-split ----
__global__ __launch_bounds__(256) void k_fc1(
    const float* __restrict__ c2p, const float* __restrict__ bn2,
    const float* __restrict__ fw, float* __restrict__ h_raw,
    float* __restrict__ part)
{
  __shared__ alignas(16) float wl[8000];
  __shared__ float s2[50], h2[50];
  __shared__ float red[4][20];
  const int tid = threadIdx.x;
  for (int i = tid; i < 2000; i += 256)
    ((float4*)wl)[i] = ((const float4*)fw)[i];
  if (tid < 50) { s2[tid] = bn2[tid]; h2[tid] = bn2[50 + tid]; }
  __syncthreads();
  const int s = tid >> 3, kc = tid & 7;
  const int sample = blockIdx.x * 32 + s;
  const float* xr = c2p + (size_t)sample * 800 + kc * 100;
  float acc[10];
  #pragma unroll
  for (int f = 0; f < 10; ++f) acc[f] = 0.f;
  #pragma unroll 5
  for (int c = 0; c < 25; ++c) {
    const int k = kc*100 + c*4;
    float4 v = *(const float4*)(xr + c*4);
    const int oc = k >> 4;
    const float sc = s2[oc], sh = h2[oc];
    v.x = relu_(v.x*sc + sh); v.y = relu_(v.y*sc + sh);
    v.z = relu_(v.z*sc + sh); v.w = relu_(v.w*sc + sh);
    #pragma unroll
    for (int f = 0; f < 10; ++f) {
      const float4 wv = *(const float4*)(wl + f*800 + k);
      acc[f] += v.x*wv.x + v.y*wv.y + v.z*wv.z + v.w*wv.w;
    }
  }
  const int lane = tid & 63, wid = tid >> 6;
  #pragma unroll
  for (int f = 0; f < 10; ++f) {
    acc[f] += __shfl_down(acc[f], 4);
    acc[f] += __shfl_down(acc[f], 2);
    acc[f] += __shfl_down(acc[f], 1);
    float a2 = (kc == 0) ? acc[f] : 0.f;
    float q2 = (kc == 0) ? acc[f]*acc[f] : 0.f;
    if (kc == 0) h_raw[(size_t)sample*10 + f] = acc[f];
    a2 += __shfl_down(a2, 32); q2 += __shfl_down(q2, 32);
    a2 += __shfl_down(a2, 16); q2 += __shfl_down(q2, 16);
    a2 += __shfl_down(a2, 8);  q2 += __shfl_down(q2, 8);
    if (lane == 0) { red[wid][f] = a2; red[wid][10+f] = q2; }
  }
  __syncthreads();
  if (tid < 20) {
    float t = 0.f;
    #pragma unroll
    for (int w2 = 0; w2 < 4; ++w2) t += red[w2][tid];
    part[(size_t)blockIdx.x*20 + tid] = t;
  }
}

// ---- BN3+ReLU, theta logits -> sigmoid, tree walk -> mu (32 samples/blk) ----
__global__ __launch_bounds__(256) void k_theta_mu(
    const float* __restrict__ h_raw, const float* __restrict__ bn3,
    const float* __restrict__ tw, const float* __restrict__ tb,
    float* __restrict__ mu)
{
  __shared__ float twt[10][256];
  __shared__ float tbl[256];
  __shared__ float hl[32][10];
  __shared__ float pl[32][256];
  const int tid = threadIdx.x, blk = blockIdx.x;
  for (int i = tid; i < 2550; i += 256) {
    const int node = i / 10, f = i - node*10;
    twt[f][node] = tw[i];
  }
  if (tid < 10) twt[tid][255] = 0.f;
  tbl[tid] = (tid < 255) ? tb[tid] : 0.f;
  for (int i = tid; i < 320; i += 256) {
    const int ss = i / 10, f = i - ss*10;
    hl[ss][f] = relu_(h_raw[(size_t)blk*320 + i] * bn3[f] + bn3[10 + f]);
  }
  __syncthreads();
  const int node = tid;
  for (int i2 = 0; i2 < 32; ++i2) {
    float h[10];
    #pragma unroll
    for (int f = 0; f < 10; ++f) h[f] = hl[i2][f];
    float d = tbl[node];
    #pragma unroll
    for (int f = 0; f < 10; ++f) d += h[f] * twt[f][node];
    pl[i2][node] = (node < 255) ? 1.f / (1.f + __expf(-d)) : 0.f;
  }
  __syncthreads();
  for (int i2 = 0; i2 < 32; ++i2) {
    float m = 1.f; int idx = 0;
    #pragma unroll
    for (int k = 0; k < 8; ++k) {
      const int dir = (tid >> (7 - k)) & 1;
      const float pv = pl[i2][idx];
      m *= dir ? pv : (1.f - pv);
      idx += dir ? (1 << (7 - k)) : 1;
    }
    mu[(size_t)(blk*32 + i2)*256 + tid] = m;
  }
}

// ---- S_raw[l,c] = sum over samples of class c of mu[b,l] ----
__global__ __launch_bounds__(256) void k_S(
    const float* __restrict__ mu, const int* __restrict__ y,
    float* __restrict__ S)
{
  const int tid = threadIdx.x;
  const int b0 = blockIdx.x * 64;
  float acc[10];
  #pragma unroll
  for (int c = 0; c < 10; ++c) acc[c] = 0.f;
  for (int s = 0; s < 64; ++s) {
    const int b = b0 + s;
    const float m = mu[(size_t)b*256 + tid];
    const int c = y[b];
    #pragma unroll
    for (int cc = 0; cc < 10; ++cc) acc[cc] += (c == cc) ? m : 0.f;
  }
  #pragma unroll
  for (int cc = 0; cc < 10; ++cc) atomicAdd(&S[tid*10 + cc], acc[cc]);
}

// ---- pi EM update (tiny, one block; thread = leaf) ----
__global__ __launch_bounds__(256) void k_pi(
    const float* __restrict__ pi, const float* __restrict__ S,
    float* __restrict__ pi_new)
{
  __shared__ float pin[2560];
  __shared__ float Pp[10];
  const int t = threadIdx.x;
  float row[10]; float rs = 0.f;
  #pragma unroll
  for (int c = 0; c < 10; ++c) { row[c] = pi[t*10 + c]; rs += row[c]; }
  #pragma unroll
  for (int c = 0; c < 10; ++c) { row[c] /= rs; pin[t*10 + c] = row[c]; }
  __syncthreads();
  if (t < 10) {
    float s = 0.f;
    for (int l = 0; l < 256; ++l) s += pin[l*10 + t];
    Pp[t] = s / 256.f;
  }
  __syncthreads();
  float hs = 0.f; float ph[10];
  #pragma unroll
  for (int c = 0; c < 10; ++c) {
    const float Sv = S[t*10 + c] / Pp[c];
    ph[c] = row[c] * Sv;
    hs += ph[c];
  }
  #pragma unroll
  for (int c = 0; c < 10; ++c) pi_new[t*10 + c] = ph[c] / hs;
}

// ---- out = log(mu @ pi_new) ----
__global__ __launch_bounds__(256) void k_out(
    const float* __restrict__ mu, const float* __restrict__ pn,
    float* __restrict__ out)
{
  __shared__ float pl[2560];
  const int tid = threadIdx.x;
  for (int i = tid; i < 2560; i += 256) pl[i] = pn[i];
  __syncthreads();
  const int gid = blockIdx.x * 256 + tid;
  const int b = gid / 10, c = gid % 10;
  const float* mr = mu + (size_t)b * 256;
  float acc = 0.f;
  for (int l = 0; l < 256; ++l) acc += mr[l] * pl[l*10 + c];
  out[gid] = logf(acc);
}

extern "C" void kernel_launch(void* const* d_in, const int* in_sizes, int n_in,
                              void* d_out, int out_size, void* d_ws, size_t ws_size,
                              hipStream_t stream)
{
  const float* x   = (const float*)d_in[0];
  const int*   y   = (const int*)  d_in[1];
  const float* c1w = (const float*)d_in[2];
  const float* c2w = (const float*)d_in[4];
  const float* g1  = (const float*)d_in[6];
  const float* be1 = (const float*)d_in[7];
  const float* g2  = (const float*)d_in[8];
  const float* be2 = (const float*)d_in[9];
  const float* fw  = (const float*)d_in[10];
  const float* g3  = (const float*)d_in[12];
  const float* be3 = (const float*)d_in[13];
  const float* thw = (const float*)d_in[14];
  const float* thb = (const float*)d_in[15];
  const float* pi  = (const float*)d_in[16];
  float* ws  = (float*)d_ws;
  float* out = (float*)d_out;

  unsigned int*   rawp1b = (unsigned int*)(ws + F_RAWP1B);
  float*          c2p    = ws + F_C2P;
  float*          part1  = ws + F_PART1;
  float*          part2  = ws + F_PART2;
  float*          part3  = ws + F_PART3;
  float*          bn1    = ws + F_BN1;
  float*          bn2    = ws + F_BN2;
  float*          bn3    = ws + F_BN3;
  float*          sraw   = ws + F_SRAW;
  float*          pinew  = ws + F_PINEW;
  unsigned short* wb2    = (unsigned short*)(ws + F_WB2);
  unsigned short* wb1    = (unsigned short*)(ws + F_WB1);
  float*          hraw   = ws + F_HRAW;   // overlays rawp1b (dead after conv2)
  float*          muB    = ws + F_MU;

  hipMemsetAsync(sraw, 0, 2560 * sizeof(float), stream);

  k_wprep1<<<4, 256, 0, stream>>>(c1w, wb1);
  k_wprep2<<<152, 256, 0, stream>>>(c2w, wb2);
  k_conv1_mfma<<<8192, 256, 0, stream>>>(x, wb1, g1, rawp1b, part1);
  k_bn_fin<<<20, 256, 0, stream>>>(part1, 8192, 20, 8192.f * 576.f, g1, be1, bn1);
  k_conv2_mfma<<<2048, 256, 0, stream>>>(rawp1b, wb2, bn1, g2, c2p, part2);
  k_bn_fin<<<50, 256, 0, stream>>>(part2, 2048, 50, 8192.f * 64.f, g2, be2, bn2);
  k_fc1<<<256, 256, 0, stream>>>(c2p, bn2, fw, hraw, part3);
  k_bn_fin<<<10, 256, 0, stream>>>(part3, 256, 10, 8192.f, g3, be3, bn3);
  k_theta_mu<<<256, 256, 0, stream>>>(hraw, bn3, thw, thb, muB);
  k_S<<<128, 256, 0, stream>>>(muB, y, sraw);
  k_pi<<<1, 256, 0, stream>>>(pi, sraw, pinew);
  k_out<<<320, 256, 0, stream>>>(muB, pinew, out);
}